// Round 6
// baseline (727.038 us; speedup 1.0000x reference)
//
#include <hip/hip_runtime.h>
#include <math.h>

#define B 2
#define L 512
#define DIN 400
#define D 256
#define H 8
#define DKK 32
#define DFF 1024
#define NL 2
#define NCLS 2
#define TPB 256
#define MAXG 512

struct Params {
  const float *feature, *pos_ind, *fmask;
  const float *w_reduce, *b_reduce, *pos_w, *pos_b;
  const float *wq, *wk, *wv, *wo, *ln1_g, *ln1_b;
  const float *w1, *b1, *w2, *b2, *ln2_g, *ln2_b, *cls_w, *cls_b;
  float *out, *x, *q, *kbuf, *vbuf, *tmp1, *tmp2, *tmp3, *tmp4, *ffn_h;
  float *T, *pbm;
  int *cnt, *gen;
  int G;
};

union SMem {
  struct { float As[2 * 32 * 20]; float Bs[2 * 16 * 68]; } g;
  struct {
    float sT[2048], qrow[256], orow[256], psh[8][64], red[8];
    int jlist[64], p0s[64], p1s[64], wcnt[8], woff[8], njs;
  } a;
};

// ---------------------------------------------------------------------------
// device-scope grid barrier (generation counting). State zeroed per launch.
// ---------------------------------------------------------------------------
__device__ __forceinline__ void gbar(int* cnt, int* gen, int G, int want) {
  __syncthreads();
  if (threadIdx.x == 0) {
    int old = __hip_atomic_fetch_add(cnt, 1, __ATOMIC_ACQ_REL,
                                     __HIP_MEMORY_SCOPE_AGENT);
    if (old == G - 1) {
      __hip_atomic_fetch_add(cnt, -G, __ATOMIC_RELAXED,
                             __HIP_MEMORY_SCOPE_AGENT);
      __hip_atomic_fetch_add(gen, 1, __ATOMIC_RELEASE,
                             __HIP_MEMORY_SCOPE_AGENT);
    } else {
      while (__hip_atomic_load(gen, __ATOMIC_ACQUIRE,
                               __HIP_MEMORY_SCOPE_AGENT) < want) {
        __builtin_amdgcn_s_sleep(2);
      }
    }
  }
  __syncthreads();
}

// ---------------------------------------------------------------------------
// double-buffered register-tiled GEMM tile (proven R5 structure), 256 thr.
// ACT: 0 none, 1 relu, 2 selu
// ---------------------------------------------------------------------------
template <int BM, int BN, int BK, int TM, int TN, int ACT>
__device__ __forceinline__ void gemm_tile(
    const float* __restrict__ A, const float* __restrict__ W,
    const float* __restrict__ bias, float* __restrict__ C, int N, int Kst,
    int m0, int n0, int kBeg, int kEnd, float* __restrict__ As,
    float* __restrict__ Bs) {
  constexpr int APAD = BK + 4;
  constexpr int BPAD = BN + 4;
  constexpr int EA = BM * BK / 256;  // 2 for BM32/BK16
  constexpr int EB = BK * BN / 256;  // 4 (BN64) or 2 (BN32)
  constexpr int ATPR = BK / EA;
  constexpr int BTPR = BN / EB;
  static_assert(EA == 2, "EA must be 2");
  int tid = threadIdx.x;
  int a_m = tid / ATPR, a_k = (tid % ATPR) * EA;
  int b_k = tid / BTPR, b_n = (tid % BTPR) * EB;
  const float* Aptr = A + (size_t)(m0 + a_m) * Kst + kBeg + a_k;
  const float* Wptr = W + (size_t)(kBeg + b_k) * N + n0 + b_n;
  int nT = (kEnd - kBeg) / BK;
  constexpr int TCOLS = BN / TN;
  int tc = tid % TCOLS, tr = tid / TCOLS;
  float acc[TM][TN];
#pragma unroll
  for (int i = 0; i < TM; ++i)
#pragma unroll
    for (int j = 0; j < TN; ++j) acc[i][j] = 0.0f;

  float2 areg = *(const float2*)Aptr;
  float breg[EB];
  if constexpr (EB == 4) {
    *(float4*)breg = *(const float4*)Wptr;
  } else {
    *(float2*)breg = *(const float2*)Wptr;
  }
  int buf = 0;
  *(float2*)&As[((size_t)0 * BM + a_m) * APAD + a_k] = areg;
  if constexpr (EB == 4) {
    *(float4*)&Bs[((size_t)0 * BK + b_k) * BPAD + b_n] = *(float4*)breg;
  } else {
    *(float2*)&Bs[((size_t)0 * BK + b_k) * BPAD + b_n] = *(float2*)breg;
  }

  for (int t = 0; t < nT; ++t) {
    __syncthreads();
    if (t + 1 < nT) {
      areg = *(const float2*)(Aptr + (t + 1) * BK);
      if constexpr (EB == 4) {
        *(float4*)breg = *(const float4*)(Wptr + (size_t)(t + 1) * BK * N);
      } else {
        *(float2*)breg = *(const float2*)(Wptr + (size_t)(t + 1) * BK * N);
      }
    }
#pragma unroll
    for (int k = 0; k < BK; ++k) {
      float a[TM];
#pragma unroll
      for (int i = 0; i < TM; ++i)
        a[i] = As[((size_t)buf * BM + tr * TM + i) * APAD + k];
      float bv[TN];
#pragma unroll
      for (int j = 0; j < TN; ++j)
        bv[j] = Bs[((size_t)buf * BK + k) * BPAD + tc * TN + j];
#pragma unroll
      for (int i = 0; i < TM; ++i)
#pragma unroll
        for (int j = 0; j < TN; ++j) acc[i][j] += a[i] * bv[j];
    }
    __syncthreads();
    if (t + 1 < nT) {
      int nb = buf ^ 1;
      *(float2*)&As[((size_t)nb * BM + a_m) * APAD + a_k] = areg;
      if constexpr (EB == 4) {
        *(float4*)&Bs[((size_t)nb * BK + b_k) * BPAD + b_n] = *(float4*)breg;
      } else {
        *(float2*)&Bs[((size_t)nb * BK + b_k) * BPAD + b_n] = *(float2*)breg;
      }
    }
    buf ^= 1;
  }
  const float s_alpha = 1.6732632423543772f, s_scale = 1.0507009873554805f;
  float bb[TN];
#pragma unroll
  for (int j = 0; j < TN; ++j)
    bb[j] = (bias != nullptr) ? bias[n0 + tc * TN + j] : 0.0f;
#pragma unroll
  for (int i = 0; i < TM; ++i) {
    int row = m0 + tr * TM + i;
    float vout[TN];
#pragma unroll
    for (int j = 0; j < TN; ++j) {
      float v = acc[i][j] + bb[j];
      if (ACT == 1) v = fmaxf(v, 0.0f);
      else if (ACT == 2) v = s_scale * (v > 0.f ? v : s_alpha * expm1f(v));
      vout[j] = v;
    }
    if constexpr (TN == 4) {
      float4 o4 = {vout[0], vout[1], vout[2], vout[3]};
      *(float4*)&C[(size_t)row * N + n0 + tc * TN] = o4;
    } else {
      float2 o2 = {vout[0], vout[1]};
      *(float2*)&C[(size_t)row * N + n0 + tc * TN] = o2;
    }
  }
}

// ---------------------------------------------------------------------------
// prep task: T[t*8+h], pbm[h]  (256 threads: 8 heads x 32 lanes, 2 r's each)
// ---------------------------------------------------------------------------
__device__ __forceinline__ void prep_task(int t, const float* __restrict__ pos_w,
                                          const float* __restrict__ pos_b,
                                          float* __restrict__ T,
                                          float* __restrict__ pbm) {
  int tid = threadIdx.x;
  int c = t >> 7;
  float p = (float)((t & 127) - 64);
  int h = tid >> 5;
  int r2 = tid & 31;
  float val = 0.f;
#pragma unroll
  for (int rr = 0; rr < 2; ++rr) {
    int r = r2 + rr * 32;
    float inv = powf(10000.0f, -(float)r * (1.0f / 64.0f));
    float a = p * inv;
    const float* ps = pos_w + (size_t)(c * 128 + r) * D + h * DKK;
    const float* pc = pos_w + (size_t)(c * 128 + 64 + r) * D + h * DKK;
    float ss = 0.f, cs = 0.f;
#pragma unroll
    for (int d = 0; d < DKK; d += 4) {
      float4 v1 = *(const float4*)&ps[d];
      float4 v2 = *(const float4*)&pc[d];
      ss += v1.x + v1.y + v1.z + v1.w;
      cs += v2.x + v2.y + v2.z + v2.w;
    }
    val += sinf(a) * ss + cosf(a) * cs;
  }
  val *= (1.0f / DKK);
#pragma unroll
  for (int m2 = 16; m2; m2 >>= 1) val += __shfl_xor(val, m2);
  if (r2 == 0) T[t * 8 + h] = val;
  if (t == 0) {
    float pv = pos_b[h * DKK + r2];
#pragma unroll
    for (int m2 = 16; m2; m2 >>= 1) pv += __shfl_xor(pv, m2);
    if (r2 == 0) pbm[h] = pv * (1.0f / DKK);
  }
}

// ---------------------------------------------------------------------------
// attn + wo + ln1 for one row bi (256 threads)
// ---------------------------------------------------------------------------
__device__ void attn_task(int bi, const Params& P, const float* __restrict__ wo_l,
                          const float* __restrict__ g1,
                          const float* __restrict__ b1v, SMem* sm) {
  int tid = threadIdx.x;
  int lane = tid & 63;
  int wv = tid >> 6;  // 0..3
  int b = bi >> 9, i = bi & 511;
  sm->a.qrow[tid] = P.q[(size_t)bi * D + tid];
  float fmi = P.fmask[bi];
  __syncthreads();
  // --- compaction of unmasked j (two sub-passes, ascending j) ---
  bool mflag[2];
  unsigned long long ball[2];
#pragma unroll
  for (int u = 0; u < 2; ++u) {
    int j = u * 256 + tid;
    float fmj = P.fmask[b * L + j];
    bool aj = (1.0f - fmj) > 0.0f;
    bool ai = (1.0f - fmi) > 0.0f;
    int di = i - j;
    bool local_np = (di >= 9) || (di <= -8);
    int ad = di < 0 ? -di : di;
    bool dil_np = (ad & 15) != 0;
    bool m = (dil_np || aj || ai) && (local_np || aj);
    mflag[u] = m;
    ball[u] = __ballot(!m);
    if (lane == 0) sm->a.wcnt[u * 4 + wv] = __popcll(ball[u]);
  }
  __syncthreads();
  if (tid == 0) {
    int s = 0;
    for (int w = 0; w < 8; ++w) { sm->a.woff[w] = s; s += sm->a.wcnt[w]; }
    sm->a.njs = s;
  }
  __syncthreads();
#pragma unroll
  for (int u = 0; u < 2; ++u) {
    if (!mflag[u]) {
      int j = u * 256 + tid;
      int slot = sm->a.woff[u * 4 + wv] +
                 __popcll(ball[u] & ((1ull << lane) - 1ull));
      sm->a.jlist[slot] = j;
      size_t pidx = ((size_t)bi * L + j) * 2;
      int p0 = (int)floorf(P.pos_ind[pidx]);
      int p1 = (int)floorf(P.pos_ind[pidx + 1]);
      sm->a.p0s[slot] = min(max(p0, -64), 63) + 64;
      sm->a.p1s[slot] = min(max(p1, -64), 63) + 192;
    }
  }
  __syncthreads();
  int nj = sm->a.njs;
  // --- scores + softmax: wave wv handles heads wv and wv+4 ---
  const float scale = 0.17677669529663687f;
#pragma unroll
  for (int hu = 0; hu < 2; ++hu) {
    int h = wv + hu * 4;
    float sc = -1e30f;
    if (lane < nj) {
      int j = sm->a.jlist[lane];
      const float4* kr4 =
          (const float4*)&P.kbuf[(size_t)(b * L + j) * D + h * DKK];
      const float4* qh4 = (const float4*)&sm->a.qrow[h * DKK];
      float dot = 0.f;
#pragma unroll
      for (int dq = 0; dq < 8; ++dq) {
        float4 av = qh4[dq], bv = kr4[dq];
        dot += av.x * bv.x + av.y * bv.y + av.z * bv.z + av.w * bv.w;
      }
      sc = dot * scale + sm->a.sT[sm->a.p0s[lane] * 8 + h] +
           sm->a.sT[sm->a.p1s[lane] * 8 + h] + P.pbm[h];
    }
    float mx = sc;
#pragma unroll
    for (int m2 = 32; m2; m2 >>= 1) mx = fmaxf(mx, __shfl_xor(mx, m2));
    float e = (lane < nj) ? expf(sc - mx) : 0.0f;
    float ssum = e;
#pragma unroll
    for (int m2 = 32; m2; m2 >>= 1) ssum += __shfl_xor(ssum, m2);
    sm->a.psh[h][lane] = e / ssum;
  }
  __syncthreads();
  // --- PV (thread owns output element tid = h2*32+d) ---
  int h2 = tid >> 5, d = tid & 31;
  float pv0 = 0.f, pv1 = 0.f;
  if (nj > 0) {
    int s2 = 0;
    for (; s2 + 1 < nj; s2 += 2) {
      pv0 += sm->a.psh[h2][s2] *
             P.vbuf[(size_t)(b * L + sm->a.jlist[s2]) * D + h2 * DKK + d];
      pv1 += sm->a.psh[h2][s2 + 1] *
             P.vbuf[(size_t)(b * L + sm->a.jlist[s2 + 1]) * D + h2 * DKK + d];
    }
    if (s2 < nj)
      pv0 += sm->a.psh[h2][s2] *
             P.vbuf[(size_t)(b * L + sm->a.jlist[s2]) * D + h2 * DKK + d];
  } else {
    for (int j = 0; j < L; ++j) pv0 += P.vbuf[(size_t)(b * L + j) * D + tid];
    pv0 *= (1.0f / L);
  }
  sm->a.orow[tid] = pv0 + pv1;
  __syncthreads();
  // --- wo: o2[c] = dot(orow, wo[:,c]), c = tid ---
  float a0 = 0.f, a1 = 0.f, a2 = 0.f, a3 = 0.f;
  const float* wc = wo_l + tid;
  for (int kk = 0; kk < D; kk += 4) {
    a0 += sm->a.orow[kk + 0] * wc[(size_t)(kk + 0) * D];
    a1 += sm->a.orow[kk + 1] * wc[(size_t)(kk + 1) * D];
    a2 += sm->a.orow[kk + 2] * wc[(size_t)(kk + 2) * D];
    a3 += sm->a.orow[kk + 3] * wc[(size_t)(kk + 3) * D];
  }
  float o2 = (a0 + a1) + (a2 + a3);
  // --- ln1 over the row ---
  float val = P.x[(size_t)bi * D + tid] + o2;
  float sum = val;
#pragma unroll
  for (int m2 = 32; m2; m2 >>= 1) sum += __shfl_xor(sum, m2);
  if (lane == 0) sm->a.red[wv] = sum;
  __syncthreads();
  float mean =
      (sm->a.red[0] + sm->a.red[1] + sm->a.red[2] + sm->a.red[3]) * (1.0f / D);
  float dd = val - mean;
  float sq = dd * dd;
#pragma unroll
  for (int m2 = 32; m2; m2 >>= 1) sq += __shfl_xor(sq, m2);
  if (lane == 0) sm->a.red[4 + wv] = sq;
  __syncthreads();
  float var =
      (sm->a.red[4] + sm->a.red[5] + sm->a.red[6] + sm->a.red[7]) * (1.0f / D);
  float rs = rsqrtf(var + 1e-5f);
  P.x[(size_t)bi * D + tid] = dd * rs * g1[tid] + b1v[tid];
  __syncthreads();
}

// ---------------------------------------------------------------------------
// ln2 over 4 rows (wave per row): x = LN(resid + t1+t2+t3+t4)*g + b
// ---------------------------------------------------------------------------
__device__ __forceinline__ void ln4_task(int grp, const Params& P,
                                         const float* __restrict__ g,
                                         const float* __restrict__ bta) {
  int t = threadIdx.x;
  int lane = t & 63;
  int row = grp * 4 + (t >> 6);
  int base = row * D + lane * 4;
  float4 r = *(const float4*)&P.x[base];
  float4 y0 = *(const float4*)&P.tmp1[base];
  float4 y1 = *(const float4*)&P.tmp2[base];
  float4 y2 = *(const float4*)&P.tmp3[base];
  float4 y3 = *(const float4*)&P.tmp4[base];
  float val[4] = {r.x + y0.x + y1.x + y2.x + y3.x,
                  r.y + y0.y + y1.y + y2.y + y3.y,
                  r.z + y0.z + y1.z + y2.z + y3.z,
                  r.w + y0.w + y1.w + y2.w + y3.w};
  float s = val[0] + val[1] + val[2] + val[3];
#pragma unroll
  for (int m = 32; m; m >>= 1) s += __shfl_xor(s, m);
  float mean = s * (1.0f / D);
  float vv = 0.f;
#pragma unroll
  for (int e = 0; e < 4; ++e) {
    float dd = val[e] - mean;
    vv += dd * dd;
  }
#pragma unroll
  for (int m = 32; m; m >>= 1) vv += __shfl_xor(vv, m);
  float rs = rsqrtf(vv * (1.0f / D) + 1e-5f);
  float4 gv = *(const float4*)&g[lane * 4];
  float4 bv = *(const float4*)&bta[lane * 4];
  float4 ov;
  ov.x = (val[0] - mean) * rs * gv.x + bv.x;
  ov.y = (val[1] - mean) * rs * gv.y + bv.y;
  ov.z = (val[2] - mean) * rs * gv.z + bv.z;
  ov.w = (val[3] - mean) * rs * gv.w + bv.w;
  *(float4*)&P.x[base] = ov;
}

// ---------------------------------------------------------------------------
// final ln2 + classifier + softmax over 4 rows (wave per row)
// ---------------------------------------------------------------------------
__device__ __forceinline__ void lncls_task(int grp, const Params& P,
                                           const float* __restrict__ g,
                                           const float* __restrict__ bta) {
  int t = threadIdx.x;
  int lane = t & 63;
  int row = grp * 4 + (t >> 6);
  int base = row * D + lane * 4;
  float4 r = *(const float4*)&P.x[base];
  float4 y0 = *(const float4*)&P.tmp1[base];
  float4 y1 = *(const float4*)&P.tmp2[base];
  float4 y2 = *(const float4*)&P.tmp3[base];
  float4 y3 = *(const float4*)&P.tmp4[base];
  float val[4] = {r.x + y0.x + y1.x + y2.x + y3.x,
                  r.y + y0.y + y1.y + y2.y + y3.y,
                  r.z + y0.z + y1.z + y2.z + y3.z,
                  r.w + y0.w + y1.w + y2.w + y3.w};
  float s = val[0] + val[1] + val[2] + val[3];
#pragma unroll
  for (int m = 32; m; m >>= 1) s += __shfl_xor(s, m);
  float mean = s * (1.0f / D);
  float vv = 0.f;
#pragma unroll
  for (int e = 0; e < 4; ++e) {
    float dd = val[e] - mean;
    vv += dd * dd;
  }
#pragma unroll
  for (int m = 32; m; m >>= 1) vv += __shfl_xor(vv, m);
  float rs = rsqrtf(vv * (1.0f / D) + 1e-5f);
  float4 gv = *(const float4*)&g[lane * 4];
  float4 bv = *(const float4*)&bta[lane * 4];
  float xv[4];
  xv[0] = (val[0] - mean) * rs * gv.x + bv.x;
  xv[1] = (val[1] - mean) * rs * gv.y + bv.y;
  xv[2] = (val[2] - mean) * rs * gv.z + bv.z;
  xv[3] = (val[3] - mean) * rs * gv.w + bv.w;
  float l0 = 0.f, l1 = 0.f;
#pragma unroll
  for (int e = 0; e < 4; ++e) {
    int col = lane * 4 + e;
    l0 += xv[e] * P.cls_w[col * NCLS + 0];
    l1 += xv[e] * P.cls_w[col * NCLS + 1];
  }
#pragma unroll
  for (int m = 32; m; m >>= 1) {
    l0 += __shfl_xor(l0, m);
    l1 += __shfl_xor(l1, m);
  }
  if (lane == 0) {
    l0 += P.cls_b[0];
    l1 += P.cls_b[1];
    float mx = fmaxf(l0, l1);
    float e0 = expf(l0 - mx), e1 = expf(l1 - mx);
    float inv = 1.0f / (e0 + e1);
    P.out[row * 2 + 0] = e0 * inv;
    P.out[row * 2 + 1] = e1 * inv;
  }
}

// ---------------------------------------------------------------------------
// persistent megakernel: all phases, grid barriers between
// ---------------------------------------------------------------------------
__global__ __launch_bounds__(TPB, 2) void mega(Params P) {
  __shared__ SMem sm;
  const int G = P.G;
  int want = 0;

  // ---- P0: reduce GEMM (selu fused) tasks 0..255  |  prep tasks 256..511 ----
  for (int task = blockIdx.x; task < 512; task += G) {
    if (task < 256) {
      int mb = task >> 3, nb = task & 7;
      gemm_tile<32, 32, 16, 2, 2, 2>(P.feature, P.w_reduce, P.b_reduce, P.x, D,
                                     DIN, mb * 32, nb * 32, 0, DIN, sm.g.As,
                                     sm.g.Bs);
    } else {
      prep_task(task - 256, P.pos_w, P.pos_b, P.T, P.pbm);
    }
    __syncthreads();
  }
  gbar(P.cnt, P.gen, G, ++want);

  for (int l = 0; l < NL; ++l) {
    const float* wq_l = P.wq + (size_t)l * D * D;
    const float* wk_l = P.wk + (size_t)l * D * D;
    const float* wv_l = P.wv + (size_t)l * D * D;
    const float* wo_l = P.wo + (size_t)l * D * D;
    const float* g1 = P.ln1_g + l * D;
    const float* b1v = P.ln1_b + l * D;
    const float* w1_l = P.w1 + (size_t)l * D * DFF;
    const float* b1_l = P.b1 + (size_t)l * DFF;
    const float* w2_l = P.w2 + (size_t)l * DFF * D;
    const float* b2_l = P.b2 + (size_t)l * D;
    const float* g2 = P.ln2_g + l * D;
    const float* b2v = P.ln2_b + l * D;

    // ---- P1: QKV (384 tasks) ----
    for (int task = blockIdx.x; task < 384; task += G) {
      int z = task >> 7, rem = task & 127;
      int mb = rem >> 2, nb = rem & 3;
      const float* W = z == 0 ? wq_l : (z == 1 ? wk_l : wv_l);
      float* C = z == 0 ? P.q : (z == 1 ? P.kbuf : P.vbuf);
      gemm_tile<32, 64, 16, 2, 4, 0>(P.x, W, nullptr, C, D, D, mb * 32,
                                     nb * 64, 0, D, sm.g.As, sm.g.Bs);
      __syncthreads();
    }
    gbar(P.cnt, P.gen, G, ++want);

    // ---- P2: attn + wo + ln1 (1024 row tasks) ----
    for (int e = threadIdx.x; e < 2048; e += TPB) sm.a.sT[e] = P.T[e];
    for (int bi = blockIdx.x; bi < B * L; bi += G)
      attn_task(bi, P, wo_l, g1, b1v, &sm);
    gbar(P.cnt, P.gen, G, ++want);

    // ---- P3: w1 + relu (512 tasks) ----
    for (int task = blockIdx.x; task < 512; task += G) {
      int mb = task >> 4, nb = task & 15;
      gemm_tile<32, 64, 16, 2, 4, 1>(P.x, w1_l, b1_l, P.ffn_h, DFF, D, mb * 32,
                                     nb * 64, 0, D, sm.g.As, sm.g.Bs);
      __syncthreads();
    }
    gbar(P.cnt, P.gen, G, ++want);

    // ---- P4: w2 split-K4 (512 tasks) ----
    for (int task = blockIdx.x; task < 512; task += G) {
      int z = task >> 7, rem = task & 127;
      int mb = rem >> 2, nb = rem & 3;
      float* Cz = z == 0 ? P.tmp1 : (z == 1 ? P.tmp2 : (z == 2 ? P.tmp3 : P.tmp4));
      gemm_tile<32, 64, 16, 2, 4, 0>(P.ffn_h, w2_l, z == 0 ? b2_l : nullptr,
                                     Cz, D, DFF, mb * 32, nb * 64, z * 256,
                                     z * 256 + 256, sm.g.As, sm.g.Bs);
      __syncthreads();
    }
    gbar(P.cnt, P.gen, G, ++want);

    // ---- P5: ln2 (+cls on last layer) ----
    if (l == NL - 1) {
      for (int task = blockIdx.x; task < 256; task += G)
        lncls_task(task, P, g2, b2v);
    } else {
      for (int task = blockIdx.x; task < 256; task += G) ln4_task(task, P, g2, b2v);
      gbar(P.cnt, P.gen, G, ++want);
    }
  }
}

extern "C" void kernel_launch(void* const* d_in, const int* in_sizes, int n_in,
                              void* d_out, int out_size, void* d_ws,
                              size_t ws_size, hipStream_t stream) {
  Params P;
  P.feature  = (const float*)d_in[0];
  P.pos_ind  = (const float*)d_in[1];
  P.fmask    = (const float*)d_in[2];
  P.w_reduce = (const float*)d_in[3];
  P.b_reduce = (const float*)d_in[4];
  P.pos_w    = (const float*)d_in[5];
  P.pos_b    = (const float*)d_in[6];
  P.wq       = (const float*)d_in[7];
  P.wk       = (const float*)d_in[8];
  P.wv       = (const float*)d_in[9];
  P.wo       = (const float*)d_in[10];
  P.ln1_g    = (const float*)d_in[11];
  P.ln1_b    = (const float*)d_in[12];
  P.w1       = (const float*)d_in[13];
  P.b1       = (const float*)d_in[14];
  P.w2       = (const float*)d_in[15];
  P.b2       = (const float*)d_in[16];
  P.ln2_g    = (const float*)d_in[17];
  P.ln2_b    = (const float*)d_in[18];
  P.cls_w    = (const float*)d_in[19];
  P.cls_b    = (const float*)d_in[20];
  P.out = (float*)d_out;

  float* ws = (float*)d_ws;
  P.x     = ws;  ws += B * L * D;
  P.q     = ws;  ws += B * L * D;
  P.kbuf  = ws;  ws += B * L * D;
  P.vbuf  = ws;  ws += B * L * D;
  P.tmp1  = ws;  ws += B * L * D;
  P.tmp2  = ws;  ws += B * L * D;
  P.tmp3  = ws;  ws += B * L * D;
  P.tmp4  = ws;  ws += B * L * D;
  P.ffn_h = ws;  ws += B * L * DFF;
  P.T     = ws;  ws += 2048;
  P.pbm   = ws;  ws += 8;
  int* bar = (int*)ws;
  P.cnt = bar;
  P.gen = bar + 1;

  int bpc = 1;
  (void)hipOccupancyMaxActiveBlocksPerMultiprocessor(&bpc, mega, TPB, 0);
  if (bpc < 1) bpc = 1;
  int G = bpc * 256;
  if (G > MAXG) G = MAXG;
  P.G = G;

  hipMemsetAsync((void*)bar, 0, 2 * sizeof(int), stream);
  mega<<<G, TPB, 0, stream>>>(P);
}

// Round 7
// 282.647 us; speedup vs baseline: 2.5722x; 2.5722x over previous
//
#include <hip/hip_runtime.h>
#include <math.h>

#define B 2
#define L 512
#define DIN 400
#define D 256
#define H 8
#define DKK 32
#define DFF 1024
#define NL 2
#define NCLS 2

// ---------------------------------------------------------------------------
// double-buffered register-tiled GEMM tile (R5-proven), 256 threads.
// ACT: 0 none, 1 relu, 2 selu
// ---------------------------------------------------------------------------
template <int BM, int BN, int BK, int TM, int TN, int ACT>
__device__ __forceinline__ void gemm_tile(
    const float* __restrict__ A, const float* __restrict__ W,
    const float* __restrict__ bias, float* __restrict__ C, int N, int Kst,
    int m0, int n0, int kBeg, int kEnd, float* __restrict__ As,
    float* __restrict__ Bs) {
  constexpr int APAD = BK + 4;
  constexpr int BPAD = BN + 4;
  constexpr int EA = BM * BK / 256;
  constexpr int EB = BK * BN / 256;
  constexpr int ATPR = BK / EA;
  constexpr int BTPR = BN / EB;
  static_assert(EA == 2, "EA must be 2");
  int tid = threadIdx.x;
  int a_m = tid / ATPR, a_k = (tid % ATPR) * EA;
  int b_k = tid / BTPR, b_n = (tid % BTPR) * EB;
  const float* Aptr = A + (size_t)(m0 + a_m) * Kst + kBeg + a_k;
  const float* Wptr = W + (size_t)(kBeg + b_k) * N + n0 + b_n;
  int nT = (kEnd - kBeg) / BK;
  constexpr int TCOLS = BN / TN;
  static_assert((BM / TM) * TCOLS == 256, "need 256 threads");
  int tc = tid % TCOLS, tr = tid / TCOLS;
  float acc[TM][TN];
#pragma unroll
  for (int i = 0; i < TM; ++i)
#pragma unroll
    for (int j = 0; j < TN; ++j) acc[i][j] = 0.0f;

  float2 areg = *(const float2*)Aptr;
  float breg[EB];
  if constexpr (EB == 4) *(float4*)breg = *(const float4*)Wptr;
  else *(float2*)breg = *(const float2*)Wptr;
  int buf = 0;
  *(float2*)&As[((size_t)0 * BM + a_m) * APAD + a_k] = areg;
  if constexpr (EB == 4)
    *(float4*)&Bs[((size_t)0 * BK + b_k) * BPAD + b_n] = *(float4*)breg;
  else
    *(float2*)&Bs[((size_t)0 * BK + b_k) * BPAD + b_n] = *(float2*)breg;

  for (int t = 0; t < nT; ++t) {
    __syncthreads();
    if (t + 1 < nT) {
      areg = *(const float2*)(Aptr + (t + 1) * BK);
      if constexpr (EB == 4)
        *(float4*)breg = *(const float4*)(Wptr + (size_t)(t + 1) * BK * N);
      else
        *(float2*)breg = *(const float2*)(Wptr + (size_t)(t + 1) * BK * N);
    }
#pragma unroll
    for (int k = 0; k < BK; ++k) {
      float a[TM];
#pragma unroll
      for (int i = 0; i < TM; ++i)
        a[i] = As[((size_t)buf * BM + tr * TM + i) * APAD + k];
      float bv[TN];
#pragma unroll
      for (int j = 0; j < TN; ++j)
        bv[j] = Bs[((size_t)buf * BK + k) * BPAD + tc * TN + j];
#pragma unroll
      for (int i = 0; i < TM; ++i)
#pragma unroll
        for (int j = 0; j < TN; ++j) acc[i][j] += a[i] * bv[j];
    }
    __syncthreads();
    if (t + 1 < nT) {
      int nb = buf ^ 1;
      *(float2*)&As[((size_t)nb * BM + a_m) * APAD + a_k] = areg;
      if constexpr (EB == 4)
        *(float4*)&Bs[((size_t)nb * BK + b_k) * BPAD + b_n] = *(float4*)breg;
      else
        *(float2*)&Bs[((size_t)nb * BK + b_k) * BPAD + b_n] = *(float2*)breg;
    }
    buf ^= 1;
  }
  const float s_alpha = 1.6732632423543772f, s_scale = 1.0507009873554805f;
  float bb[TN];
#pragma unroll
  for (int j = 0; j < TN; ++j)
    bb[j] = (bias != nullptr) ? bias[n0 + tc * TN + j] : 0.0f;
#pragma unroll
  for (int i = 0; i < TM; ++i) {
    int row = m0 + tr * TM + i;
    float vout[TN];
#pragma unroll
    for (int j = 0; j < TN; ++j) {
      float v = acc[i][j] + bb[j];
      if (ACT == 1) v = fmaxf(v, 0.0f);
      else if (ACT == 2) v = s_scale * (v > 0.f ? v : s_alpha * expm1f(v));
      vout[j] = v;
    }
    if constexpr (TN == 4) {
      float4 o4 = {vout[0], vout[1], vout[2], vout[3]};
      *(float4*)&C[(size_t)row * N + n0 + tc * TN] = o4;
    } else {
      float2 o2 = {vout[0], vout[1]};
      *(float2*)&C[(size_t)row * N + n0 + tc * TN] = o2;
    }
  }
}

// ---------------------------------------------------------------------------
// prep task (256 thr): T[t*8+h], pbm[h]
// ---------------------------------------------------------------------------
__device__ __forceinline__ void prep_task(int t, const float* __restrict__ pos_w,
                                          const float* __restrict__ pos_b,
                                          float* __restrict__ T,
                                          float* __restrict__ pbm) {
  int tid = threadIdx.x;
  int c = t >> 7;
  float p = (float)((t & 127) - 64);
  int h = tid >> 5;
  int r2 = tid & 31;
  float val = 0.f;
#pragma unroll
  for (int rr = 0; rr < 2; ++rr) {
    int r = r2 + rr * 32;
    float inv = powf(10000.0f, -(float)r * (1.0f / 64.0f));
    float a = p * inv;
    const float* ps = pos_w + (size_t)(c * 128 + r) * D + h * DKK;
    const float* pc = pos_w + (size_t)(c * 128 + 64 + r) * D + h * DKK;
    float ss = 0.f, cs = 0.f;
#pragma unroll
    for (int d = 0; d < DKK; d += 4) {
      float4 v1 = *(const float4*)&ps[d];
      float4 v2 = *(const float4*)&pc[d];
      ss += v1.x + v1.y + v1.z + v1.w;
      cs += v2.x + v2.y + v2.z + v2.w;
    }
    val += sinf(a) * ss + cosf(a) * cs;
  }
  val *= (1.0f / DKK);
#pragma unroll
  for (int m2 = 16; m2; m2 >>= 1) val += __shfl_xor(val, m2);
  if (r2 == 0) T[t * 8 + h] = val;
  if (t == 0) {
    float pv = pos_b[h * DKK + r2];
#pragma unroll
    for (int m2 = 16; m2; m2 >>= 1) pv += __shfl_xor(pv, m2);
    if (r2 == 0) pbm[h] = pv * (1.0f / DKK);
  }
}

// ---------------------------------------------------------------------------
// K1: reduce GEMM (selu) tasks 0..255 | prep tasks 256..511
// ---------------------------------------------------------------------------
__global__ __launch_bounds__(256) void k_reduce_prep(
    const float* __restrict__ feature, const float* __restrict__ w_reduce,
    const float* __restrict__ b_reduce, float* __restrict__ x,
    const float* __restrict__ pos_w, const float* __restrict__ pos_b,
    float* __restrict__ T, float* __restrict__ pbm) {
  __shared__ float As[2 * 32 * 20];
  __shared__ float Bs[2 * 16 * 36];
  int task = blockIdx.x;
  if (task < 256) {
    int mb = task >> 3, nb = task & 7;
    gemm_tile<32, 32, 16, 2, 2, 2>(feature, w_reduce, b_reduce, x, D, DIN,
                                   mb * 32, nb * 32, 0, DIN, As, Bs);
  } else {
    prep_task(task - 256, pos_w, pos_b, T, pbm);
  }
}

// ---------------------------------------------------------------------------
// K2: qkv GEMM (z selects matrix), grid (32,4,3)
// ---------------------------------------------------------------------------
__global__ __launch_bounds__(256) void k_qkv(
    const float* __restrict__ x, const float* __restrict__ wq_l,
    const float* __restrict__ wk_l, const float* __restrict__ wv_l,
    float* __restrict__ q, float* __restrict__ kbuf, float* __restrict__ vbuf) {
  __shared__ float As[2 * 32 * 20];
  __shared__ float Bs[2 * 16 * 68];
  int z = blockIdx.z;
  const float* W = z == 0 ? wq_l : (z == 1 ? wk_l : wv_l);
  float* C = z == 0 ? q : (z == 1 ? kbuf : vbuf);
  gemm_tile<32, 64, 16, 2, 4, 0>(x, W, nullptr, C, D, D, blockIdx.x * 32,
                                 blockIdx.y * 64, 0, D, As, Bs);
}

// ---------------------------------------------------------------------------
// K3: attn + wo + ln1 for one row per block (256 threads, mega-proven body)
// ---------------------------------------------------------------------------
__global__ __launch_bounds__(256) void k_attn(
    const float* __restrict__ q, const float* __restrict__ kk,
    const float* __restrict__ vv, const float* __restrict__ pos_ind,
    const float* __restrict__ fmask, const float* __restrict__ Tg,
    const float* __restrict__ pbm, float* __restrict__ xio,
    const float* __restrict__ wo_l, const float* __restrict__ g1,
    const float* __restrict__ b1v) {
  __shared__ float sT[2048];
  __shared__ float qrow[256];
  __shared__ float orow[256];
  __shared__ float psh[8][64];
  __shared__ float red[8];
  __shared__ int jlist[64], p0s[64], p1s[64], wcnt[8], woff[8], njs;
  int tid = threadIdx.x;
  int lane = tid & 63;
  int wv = tid >> 6;
  int bi = blockIdx.x;
  int b = bi >> 9, i = bi & 511;
  for (int e = tid; e < 2048; e += 256) sT[e] = Tg[e];
  qrow[tid] = q[(size_t)bi * D + tid];
  float fmi = fmask[bi];
  __syncthreads();
  bool mflag[2];
  unsigned long long ball[2];
#pragma unroll
  for (int u = 0; u < 2; ++u) {
    int j = u * 256 + tid;
    float fmj = fmask[b * L + j];
    bool aj = (1.0f - fmj) > 0.0f;
    bool ai = (1.0f - fmi) > 0.0f;
    int di = i - j;
    bool local_np = (di >= 9) || (di <= -8);
    int ad = di < 0 ? -di : di;
    bool dil_np = (ad & 15) != 0;
    bool m = (dil_np || aj || ai) && (local_np || aj);
    mflag[u] = m;
    ball[u] = __ballot(!m);
    if (lane == 0) wcnt[u * 4 + wv] = __popcll(ball[u]);
  }
  __syncthreads();
  if (tid == 0) {
    int s = 0;
    for (int w = 0; w < 8; ++w) { woff[w] = s; s += wcnt[w]; }
    njs = s;
  }
  __syncthreads();
#pragma unroll
  for (int u = 0; u < 2; ++u) {
    if (!mflag[u]) {
      int j = u * 256 + tid;
      int slot = woff[u * 4 + wv] + __popcll(ball[u] & ((1ull << lane) - 1ull));
      jlist[slot] = j;
      size_t pidx = ((size_t)bi * L + j) * 2;
      int p0 = (int)floorf(pos_ind[pidx]);
      int p1 = (int)floorf(pos_ind[pidx + 1]);
      p0s[slot] = min(max(p0, -64), 63) + 64;
      p1s[slot] = min(max(p1, -64), 63) + 192;
    }
  }
  __syncthreads();
  int nj = njs;
  const float scale = 0.17677669529663687f;
#pragma unroll
  for (int hu = 0; hu < 2; ++hu) {
    int h = wv + hu * 4;
    float sc = -1e30f;
    if (lane < nj) {
      int j = jlist[lane];
      const float4* kr4 = (const float4*)&kk[(size_t)(b * L + j) * D + h * DKK];
      const float4* qh4 = (const float4*)&qrow[h * DKK];
      float dot = 0.f;
#pragma unroll
      for (int dq = 0; dq < 8; ++dq) {
        float4 av = qh4[dq], bv = kr4[dq];
        dot += av.x * bv.x + av.y * bv.y + av.z * bv.z + av.w * bv.w;
      }
      sc = dot * scale + sT[p0s[lane] * 8 + h] + sT[p1s[lane] * 8 + h] + pbm[h];
    }
    float mx = sc;
#pragma unroll
    for (int m2 = 32; m2; m2 >>= 1) mx = fmaxf(mx, __shfl_xor(mx, m2));
    float e = (lane < nj) ? expf(sc - mx) : 0.0f;
    float ssum = e;
#pragma unroll
    for (int m2 = 32; m2; m2 >>= 1) ssum += __shfl_xor(ssum, m2);
    psh[h][lane] = e / ssum;
  }
  __syncthreads();
  int h2 = tid >> 5, d = tid & 31;
  float pv0 = 0.f, pv1 = 0.f;
  if (nj > 0) {
    int s2 = 0;
    for (; s2 + 1 < nj; s2 += 2) {
      pv0 += psh[h2][s2] * vv[(size_t)(b * L + jlist[s2]) * D + h2 * DKK + d];
      pv1 += psh[h2][s2 + 1] *
             vv[(size_t)(b * L + jlist[s2 + 1]) * D + h2 * DKK + d];
    }
    if (s2 < nj)
      pv0 += psh[h2][s2] * vv[(size_t)(b * L + jlist[s2]) * D + h2 * DKK + d];
  } else {
    for (int j = 0; j < L; ++j) pv0 += vv[(size_t)(b * L + j) * D + tid];
    pv0 *= (1.0f / L);
  }
  orow[tid] = pv0 + pv1;
  __syncthreads();
  float a0 = 0.f, a1 = 0.f, a2 = 0.f, a3 = 0.f;
  const float* wc = wo_l + tid;
  for (int kx = 0; kx < D; kx += 4) {
    a0 += orow[kx + 0] * wc[(size_t)(kx + 0) * D];
    a1 += orow[kx + 1] * wc[(size_t)(kx + 1) * D];
    a2 += orow[kx + 2] * wc[(size_t)(kx + 2) * D];
    a3 += orow[kx + 3] * wc[(size_t)(kx + 3) * D];
  }
  float o2 = (a0 + a1) + (a2 + a3);
  float val = xio[(size_t)bi * D + tid] + o2;
  float sum = val;
#pragma unroll
  for (int m2 = 32; m2; m2 >>= 1) sum += __shfl_xor(sum, m2);
  if (lane == 0) red[wv] = sum;
  __syncthreads();
  float mean = (red[0] + red[1] + red[2] + red[3]) * (1.0f / D);
  float dd = val - mean;
  float sq = dd * dd;
#pragma unroll
  for (int m2 = 32; m2; m2 >>= 1) sq += __shfl_xor(sq, m2);
  if (lane == 0) red[4 + wv] = sq;
  __syncthreads();
  float var = (red[4] + red[5] + red[6] + red[7]) * (1.0f / D);
  float rs = rsqrtf(var + 1e-5f);
  xio[(size_t)bi * D + tid] = dd * rs * g1[tid] + b1v[tid];
}

// ---------------------------------------------------------------------------
// K4: w1 + relu, grid (32,16)
// ---------------------------------------------------------------------------
__global__ __launch_bounds__(256) void k_w1(const float* __restrict__ x,
                                            const float* __restrict__ w1_l,
                                            const float* __restrict__ b1_l,
                                            float* __restrict__ ffn_h) {
  __shared__ float As[2 * 32 * 20];
  __shared__ float Bs[2 * 16 * 68];
  gemm_tile<32, 64, 16, 2, 4, 1>(x, w1_l, b1_l, ffn_h, DFF, D,
                                 blockIdx.x * 32, blockIdx.y * 64, 0, D, As,
                                 Bs);
}

// ---------------------------------------------------------------------------
// K5: w2 split-K4, grid (32,4,4)
// ---------------------------------------------------------------------------
__global__ __launch_bounds__(256) void k_w2(
    const float* __restrict__ ffn_h, const float* __restrict__ w2_l,
    const float* __restrict__ b2_l, float* __restrict__ t1,
    float* __restrict__ t2, float* __restrict__ t3, float* __restrict__ t4) {
  __shared__ float As[2 * 32 * 20];
  __shared__ float Bs[2 * 16 * 68];
  int z = blockIdx.z;
  float* Cz = z == 0 ? t1 : (z == 1 ? t2 : (z == 2 ? t3 : t4));
  gemm_tile<32, 64, 16, 2, 4, 0>(ffn_h, w2_l, z == 0 ? b2_l : nullptr, Cz, D,
                                 DFF, blockIdx.x * 32, blockIdx.y * 64,
                                 z * 256, z * 256 + 256, As, Bs);
}

// ---------------------------------------------------------------------------
// K6: ln2(l) fused with qkv(l+1). grid (32,4,3).
// Each block recomputes LN2 of its 32 rows into LDS, GEMMs from LDS.
// Blocks with (y==0,z==0) also store the LN'd rows to xnew.
// ---------------------------------------------------------------------------
__global__ __launch_bounds__(256) void k_ln2qkv(
    const float* __restrict__ xold, const float* __restrict__ t1,
    const float* __restrict__ t2, const float* __restrict__ t3,
    const float* __restrict__ t4, const float* __restrict__ g,
    const float* __restrict__ bta, const float* __restrict__ wq_l,
    const float* __restrict__ wk_l, const float* __restrict__ wv_l,
    float* __restrict__ q, float* __restrict__ kbuf, float* __restrict__ vbuf,
    float* __restrict__ xnew) {
  __shared__ float xs[32][260];
  __shared__ float Bs[2][16][68];
  int tid = threadIdx.x;
  int lane = tid & 63, wv = tid >> 6;
  int m0 = blockIdx.x * 32;
  // --- LN2 for rows m0..m0+31 (wave per row, 8 rows each) ---
  for (int r8 = 0; r8 < 8; ++r8) {
    int lr = wv * 8 + r8;
    int base = (m0 + lr) * D + lane * 4;
    float4 r = *(const float4*)&xold[base];
    float4 y0 = *(const float4*)&t1[base];
    float4 y1 = *(const float4*)&t2[base];
    float4 y2 = *(const float4*)&t3[base];
    float4 y3 = *(const float4*)&t4[base];
    float val[4] = {r.x + y0.x + y1.x + y2.x + y3.x,
                    r.y + y0.y + y1.y + y2.y + y3.y,
                    r.z + y0.z + y1.z + y2.z + y3.z,
                    r.w + y0.w + y1.w + y2.w + y3.w};
    float s = val[0] + val[1] + val[2] + val[3];
#pragma unroll
    for (int m = 32; m; m >>= 1) s += __shfl_xor(s, m);
    float mean = s * (1.0f / D);
    float vvv = 0.f;
#pragma unroll
    for (int e = 0; e < 4; ++e) {
      float dd = val[e] - mean;
      vvv += dd * dd;
    }
#pragma unroll
    for (int m = 32; m; m >>= 1) vvv += __shfl_xor(vvv, m);
    float rs = rsqrtf(vvv * (1.0f / D) + 1e-5f);
    float4 gv = *(const float4*)&g[lane * 4];
    float4 bv = *(const float4*)&bta[lane * 4];
    float4 ov;
    ov.x = (val[0] - mean) * rs * gv.x + bv.x;
    ov.y = (val[1] - mean) * rs * gv.y + bv.y;
    ov.z = (val[2] - mean) * rs * gv.z + bv.z;
    ov.w = (val[3] - mean) * rs * gv.w + bv.w;
    *(float4*)&xs[lr][lane * 4] = ov;
  }
  __syncthreads();
  // --- qkv GEMM from LDS A ---
  int z = blockIdx.z;
  const float* W = z == 0 ? wq_l : (z == 1 ? wk_l : wv_l);
  float* C = z == 0 ? q : (z == 1 ? kbuf : vbuf);
  int n0 = blockIdx.y * 64;
  int b_k = tid >> 4, b_n = (tid & 15) * 4;
  const float* Wptr = W + (size_t)b_k * D + n0 + b_n;
  int tc = tid & 15, tr = tid >> 4;
  float acc[2][4] = {{0, 0, 0, 0}, {0, 0, 0, 0}};
  float4 breg = *(const float4*)Wptr;
  int buf = 0;
  *(float4*)&Bs[0][b_k][b_n] = breg;
  for (int t = 0; t < 16; ++t) {
    __syncthreads();
    if (t + 1 < 16) breg = *(const float4*)(Wptr + (size_t)(t + 1) * 16 * D);
#pragma unroll
    for (int k = 0; k < 16; ++k) {
      float a0 = xs[tr * 2 + 0][t * 16 + k];
      float a1 = xs[tr * 2 + 1][t * 16 + k];
      float4 bvv = *(const float4*)&Bs[buf][k][tc * 4];
      acc[0][0] += a0 * bvv.x; acc[0][1] += a0 * bvv.y;
      acc[0][2] += a0 * bvv.z; acc[0][3] += a0 * bvv.w;
      acc[1][0] += a1 * bvv.x; acc[1][1] += a1 * bvv.y;
      acc[1][2] += a1 * bvv.z; acc[1][3] += a1 * bvv.w;
    }
    __syncthreads();
    if (t + 1 < 16) *(float4*)&Bs[buf ^ 1][b_k][b_n] = breg;
    buf ^= 1;
  }
#pragma unroll
  for (int i = 0; i < 2; ++i) {
    float4 o4 = {acc[i][0], acc[i][1], acc[i][2], acc[i][3]};
    *(float4*)&C[(size_t)(m0 + tr * 2 + i) * D + n0 + tc * 4] = o4;
  }
  // --- write xnew (one task per row-group) ---
  if (blockIdx.y == 0 && z == 0) {
    for (int e = tid; e < 2048; e += 256) {
      int lr = e >> 6, c4 = e & 63;
      *(float4*)&xnew[(size_t)(m0 + lr) * D + c4 * 4] =
          *(const float4*)&xs[lr][c4 * 4];
    }
  }
}

// ---------------------------------------------------------------------------
// K7: final ln2 + classifier + softmax (wave per row, 4 rows/block)
// ---------------------------------------------------------------------------
__global__ __launch_bounds__(256) void k_lncls(
    const float* __restrict__ resid, const float* __restrict__ y0,
    const float* __restrict__ y1, const float* __restrict__ y2,
    const float* __restrict__ y3, const float* __restrict__ g,
    const float* __restrict__ bta, const float* __restrict__ cw,
    const float* __restrict__ cb, float* __restrict__ out) {
  int t = threadIdx.x;
  int lane = t & 63;
  int row = blockIdx.x * 4 + (t >> 6);
  int base = row * D + lane * 4;
  float4 r = *(const float4*)&resid[base];
  float4 a = *(const float4*)&y0[base];
  float4 c = *(const float4*)&y1[base];
  float4 d2 = *(const float4*)&y2[base];
  float4 e2 = *(const float4*)&y3[base];
  float val[4] = {r.x + a.x + c.x + d2.x + e2.x,
                  r.y + a.y + c.y + d2.y + e2.y,
                  r.z + a.z + c.z + d2.z + e2.z,
                  r.w + a.w + c.w + d2.w + e2.w};
  float s = val[0] + val[1] + val[2] + val[3];
#pragma unroll
  for (int m = 32; m; m >>= 1) s += __shfl_xor(s, m);
  float mean = s * (1.0f / D);
  float vv = 0.f;
#pragma unroll
  for (int e = 0; e < 4; ++e) {
    float dd = val[e] - mean;
    vv += dd * dd;
  }
#pragma unroll
  for (int m = 32; m; m >>= 1) vv += __shfl_xor(vv, m);
  float rs = rsqrtf(vv * (1.0f / D) + 1e-5f);
  float4 gv = *(const float4*)&g[lane * 4];
  float4 bv = *(const float4*)&bta[lane * 4];
  float xv[4];
  xv[0] = (val[0] - mean) * rs * gv.x + bv.x;
  xv[1] = (val[1] - mean) * rs * gv.y + bv.y;
  xv[2] = (val[2] - mean) * rs * gv.z + bv.z;
  xv[3] = (val[3] - mean) * rs * gv.w + bv.w;
  float l0 = 0.f, l1 = 0.f;
#pragma unroll
  for (int e = 0; e < 4; ++e) {
    int col = lane * 4 + e;
    l0 += xv[e] * cw[col * NCLS + 0];
    l1 += xv[e] * cw[col * NCLS + 1];
  }
#pragma unroll
  for (int m = 32; m; m >>= 1) {
    l0 += __shfl_xor(l0, m);
    l1 += __shfl_xor(l1, m);
  }
  if (lane == 0) {
    l0 += cb[0];
    l1 += cb[1];
    float mx = fmaxf(l0, l1);
    float e0 = expf(l0 - mx), e1 = expf(l1 - mx);
    float inv = 1.0f / (e0 + e1);
    out[row * 2 + 0] = e0 * inv;
    out[row * 2 + 1] = e1 * inv;
  }
}

extern "C" void kernel_launch(void* const* d_in, const int* in_sizes, int n_in,
                              void* d_out, int out_size, void* d_ws,
                              size_t ws_size, hipStream_t stream) {
  const float* feature  = (const float*)d_in[0];
  const float* pos_ind  = (const float*)d_in[1];
  const float* fmaskp   = (const float*)d_in[2];
  const float* w_reduce = (const float*)d_in[3];
  const float* b_reduce = (const float*)d_in[4];
  const float* pos_w    = (const float*)d_in[5];
  const float* pos_b    = (const float*)d_in[6];
  const float* wq       = (const float*)d_in[7];
  const float* wk       = (const float*)d_in[8];
  const float* wv       = (const float*)d_in[9];
  const float* wo       = (const float*)d_in[10];
  const float* ln1_g    = (const float*)d_in[11];
  const float* ln1_b    = (const float*)d_in[12];
  const float* w1       = (const float*)d_in[13];
  const float* b1       = (const float*)d_in[14];
  const float* w2       = (const float*)d_in[15];
  const float* b2       = (const float*)d_in[16];
  const float* ln2_g    = (const float*)d_in[17];
  const float* ln2_b    = (const float*)d_in[18];
  const float* cls_w    = (const float*)d_in[19];
  const float* cls_b    = (const float*)d_in[20];
  float* out = (float*)d_out;

  float* ws = (float*)d_ws;
  float* x0    = ws;  ws += B * L * D;
  float* x1    = ws;  ws += B * L * D;
  float* q     = ws;  ws += B * L * D;
  float* kbuf  = ws;  ws += B * L * D;
  float* vbuf  = ws;  ws += B * L * D;
  float* tmp1  = ws;  ws += B * L * D;
  float* tmp2  = ws;  ws += B * L * D;
  float* tmp3  = ws;  ws += B * L * D;
  float* tmp4  = ws;  ws += B * L * D;
  float* ffn_h = ws;  ws += B * L * DFF;
  float* T     = ws;  ws += 2048;
  float* pbm   = ws;  ws += 8;

  // K1: reduce + prep
  k_reduce_prep<<<512, 256, 0, stream>>>(feature, w_reduce, b_reduce, x0,
                                         pos_w, pos_b, T, pbm);
  // layer 0
  k_qkv<<<dim3(32, 4, 3), 256, 0, stream>>>(x0, wq, wk, wv, q, kbuf, vbuf);
  k_attn<<<B * L, 256, 0, stream>>>(q, kbuf, vbuf, pos_ind, fmaskp, T, pbm,
                                    x0, wo, ln1_g, ln1_b);
  k_w1<<<dim3(32, 16), 256, 0, stream>>>(x0, w1, b1, ffn_h);
  k_w2<<<dim3(32, 4, 4), 256, 0, stream>>>(ffn_h, w2, b2, tmp1, tmp2, tmp3,
                                           tmp4);
  // ln2(l0) + qkv(l1)
  k_ln2qkv<<<dim3(32, 4, 3), 256, 0, stream>>>(
      x0, tmp1, tmp2, tmp3, tmp4, ln2_g, ln2_b, wq + D * D, wk + D * D,
      wv + D * D, q, kbuf, vbuf, x1);
  // layer 1
  k_attn<<<B * L, 256, 0, stream>>>(q, kbuf, vbuf, pos_ind, fmaskp, T, pbm,
                                    x1, wo + D * D, ln1_g + D, ln1_b + D);
  k_w1<<<dim3(32, 16), 256, 0, stream>>>(x1, w1 + D * DFF, b1 + DFF, ffn_h);
  k_w2<<<dim3(32, 4, 4), 256, 0, stream>>>(ffn_h, w2 + DFF * D, b2 + D, tmp1,
                                           tmp2, tmp3, tmp4);
  k_lncls<<<B * L / 4, 256, 0, stream>>>(x1, tmp1, tmp2, tmp3, tmp4,
                                         ln2_g + D, ln2_b + D, cls_w, cls_b,
                                         out);
}

// Round 8
// 146.346 us; speedup vs baseline: 4.9680x; 1.9314x over previous
//
#include <hip/hip_runtime.h>
#include <math.h>

#define B 2
#define L 512
#define DIN 400
#define D 256
#define H 8
#define DKK 32
#define DFF 1024
#define NL 2
#define NCLS 2

// ---------------------------------------------------------------------------
// prep: T[t*8+h] = sum_r sin(p*inv[r])*pwm[c*128+r][h] + cos(p*inv[r])*pwm[c*128+64+r][h]
// grid 256 blocks (one per t), 512 threads = 8 waves (one per h), lane = r.
// ---------------------------------------------------------------------------
__global__ __launch_bounds__(512) void prep_kernel(
    const float* __restrict__ pos_w, const float* __restrict__ pos_b,
    float* __restrict__ T, float* __restrict__ pbm) {
  int t = blockIdx.x;
  int c = t >> 7;
  float p = (float)((t & 127) - 64);
  int h = threadIdx.x >> 6;
  int r = threadIdx.x & 63;
  float inv = powf(10000.0f, -(float)r * (1.0f / 64.0f));
  float a = p * inv;
  const float* ps = pos_w + (size_t)(c * 128 + r) * D + h * DKK;
  const float* pc = pos_w + (size_t)(c * 128 + 64 + r) * D + h * DKK;
  float ss = 0.f, cs = 0.f;
#pragma unroll
  for (int d = 0; d < DKK; d += 4) {
    float4 v1 = *(const float4*)&ps[d];
    float4 v2 = *(const float4*)&pc[d];
    ss += v1.x + v1.y + v1.z + v1.w;
    cs += v2.x + v2.y + v2.z + v2.w;
  }
  float val = (sinf(a) * ss + cosf(a) * cs) * (1.0f / DKK);
#pragma unroll
  for (int m = 32; m; m >>= 1) val += __shfl_xor(val, m);
  if (r == 0) T[t * 8 + h] = val;
  if (t == 0) {
    float pv = (r < DKK) ? pos_b[h * DKK + r] : 0.0f;
#pragma unroll
    for (int m = 32; m; m >>= 1) pv += __shfl_xor(pv, m);
    if (r == 0) pbm[h] = pv * (1.0f / DKK);
  }
}

// ---------------------------------------------------------------------------
// double-buffered register-tiled GEMM (R5-verbatim): C = act(A @ W + bias)
// BM=32, BN=64, BK=16, TM=2, TN=4; 256 threads.
// MODE 0: single. MODE 1: z selects (Wa->Ca)/(Wb->Cb)/(Wc->Cc).
// MODE 2: split-K 2 at kMid. MODE 3: split-K 4.
// ACT: 0 none, 1 relu (MODE==0 only)
// ---------------------------------------------------------------------------
template <int ACT, int MODE>
__global__ __launch_bounds__(256) void gemm_kernel(
    const float* __restrict__ A, const float* __restrict__ Wa,
    const float* __restrict__ Wb, const float* __restrict__ Wc,
    const float* __restrict__ bias, float* __restrict__ Ca,
    float* __restrict__ Cb, float* __restrict__ Cc, float* __restrict__ Cd,
    int M, int N, int K, int kMid) {
  __shared__ float As[2][32][20];
  __shared__ float Bs[2][16][68];
  int tid = threadIdx.x;
  int m0 = blockIdx.x * 32;
  int n0 = blockIdx.y * 64;
  const float* W = Wa;
  float* C = Ca;
  int kBeg = 0, kEnd = K;
  bool useBias = (bias != nullptr);
  if (MODE == 1) {
    W = blockIdx.z == 0 ? Wa : (blockIdx.z == 1 ? Wb : Wc);
    C = blockIdx.z == 0 ? Ca : (blockIdx.z == 1 ? Cb : Cc);
  } else if (MODE == 2) {
    kBeg = blockIdx.z == 0 ? 0 : kMid;
    kEnd = blockIdx.z == 0 ? kMid : K;
    C = blockIdx.z == 0 ? Ca : Cb;
    if (blockIdx.z != 0) useBias = false;
  } else if (MODE == 3) {
    int q = K / 4;
    kBeg = blockIdx.z * q;
    kEnd = kBeg + q;
    C = blockIdx.z == 0 ? Ca
        : (blockIdx.z == 1 ? Cb : (blockIdx.z == 2 ? Cc : Cd));
    if (blockIdx.z != 0) useBias = false;
  }
  // staging maps
  int a_m = tid >> 3;            // 0..31
  int a_k = (tid & 7) * 2;       // 0..14 (float2)
  int b_k = tid >> 4;            // 0..15
  int b_n = (tid & 15) * 4;      // float4
  const float* Aptr = A + (size_t)(m0 + a_m) * K + kBeg + a_k;
  const float* Wptr = W + (size_t)(kBeg + b_k) * N + n0 + b_n;
  int nT = (kEnd - kBeg) / 16;
  int tc = tid & 15;
  int tr = tid >> 4;
  float acc[2][4];
#pragma unroll
  for (int i = 0; i < 2; ++i)
#pragma unroll
    for (int j = 0; j < 4; ++j) acc[i][j] = 0.0f;

  float2 areg = *(const float2*)Aptr;
  float4 breg = *(const float4*)Wptr;
  int buf = 0;
  *(float2*)&As[0][a_m][a_k] = areg;
  *(float4*)&Bs[0][b_k][b_n] = breg;

  for (int t = 0; t < nT; ++t) {
    __syncthreads();  // As/Bs[buf] visible; prior reads of buf^1 complete
    if (t + 1 < nT) {
      areg = *(const float2*)(Aptr + (t + 1) * 16);
      breg = *(const float4*)(Wptr + (size_t)(t + 1) * 16 * N);
    }
#pragma unroll
    for (int k = 0; k < 16; ++k) {
      float a0 = As[buf][tr * 2 + 0][k];
      float a1 = As[buf][tr * 2 + 1][k];
      float4 b = *(const float4*)&Bs[buf][k][tc * 4];
      acc[0][0] += a0 * b.x; acc[0][1] += a0 * b.y;
      acc[0][2] += a0 * b.z; acc[0][3] += a0 * b.w;
      acc[1][0] += a1 * b.x; acc[1][1] += a1 * b.y;
      acc[1][2] += a1 * b.z; acc[1][3] += a1 * b.w;
    }
    __syncthreads();  // all reads of As/Bs[buf] done
    if (t + 1 < nT) {
      *(float2*)&As[buf ^ 1][a_m][a_k] = areg;
      *(float4*)&Bs[buf ^ 1][b_k][b_n] = breg;
    }
    buf ^= 1;
  }
  float bb[4];
#pragma unroll
  for (int j = 0; j < 4; ++j) bb[j] = useBias ? bias[n0 + tc * 4 + j] : 0.0f;
#pragma unroll
  for (int i = 0; i < 2; ++i) {
    int row = m0 + tr * 2 + i;
    float4 outv;
    float v0 = acc[i][0] + bb[0], v1 = acc[i][1] + bb[1];
    float v2 = acc[i][2] + bb[2], v3 = acc[i][3] + bb[3];
    if (MODE == 0 && ACT == 1) {
      v0 = fmaxf(v0, 0.f); v1 = fmaxf(v1, 0.f);
      v2 = fmaxf(v2, 0.f); v3 = fmaxf(v3, 0.f);
    }
    outv.x = v0; outv.y = v1; outv.z = v2; outv.w = v3;
    *(float4*)&C[(size_t)row * N + n0 + tc * 4] = outv;
  }
}

// ---------------------------------------------------------------------------
// x = selu(a + b) elementwise (reduce-layer partial sum), float4
// ---------------------------------------------------------------------------
__global__ __launch_bounds__(256) void selu_add_kernel(
    const float* __restrict__ a, const float* __restrict__ b,
    float* __restrict__ x) {
  int e = (blockIdx.x * 256 + threadIdx.x) * 4;
  float4 va = *(const float4*)&a[e];
  float4 vb = *(const float4*)&b[e];
  const float s_alpha = 1.6732632423543772f, s_scale = 1.0507009873554805f;
  float4 o;
  float v;
  v = va.x + vb.x; o.x = s_scale * (v > 0.f ? v : s_alpha * expm1f(v));
  v = va.y + vb.y; o.y = s_scale * (v > 0.f ? v : s_alpha * expm1f(v));
  v = va.z + vb.z; o.z = s_scale * (v > 0.f ? v : s_alpha * expm1f(v));
  v = va.w + vb.w; o.w = s_scale * (v > 0.f ? v : s_alpha * expm1f(v));
  *(float4*)&x[e] = o;
}

// ---------------------------------------------------------------------------
// fused attn + wo + ln1, one row per block (256 threads) — R6/R7-proven body
// ---------------------------------------------------------------------------
__global__ __launch_bounds__(256) void k_attn(
    const float* __restrict__ q, const float* __restrict__ kk,
    const float* __restrict__ vv, const float* __restrict__ pos_ind,
    const float* __restrict__ fmask, const float* __restrict__ Tg,
    const float* __restrict__ pbm, float* __restrict__ xio,
    const float* __restrict__ wo_l, const float* __restrict__ g1,
    const float* __restrict__ b1v) {
  __shared__ float sT[2048];
  __shared__ float qrow[256];
  __shared__ float orow[256];
  __shared__ float psh[8][64];
  __shared__ float red[8];
  __shared__ int jlist[64], p0s[64], p1s[64], wcnt[8], woff[8], njs;
  int tid = threadIdx.x;
  int lane = tid & 63;
  int wv = tid >> 6;
  int bi = blockIdx.x;
  int b = bi >> 9, i = bi & 511;
  for (int e = tid; e < 2048; e += 256) sT[e] = Tg[e];
  qrow[tid] = q[(size_t)bi * D + tid];
  float fmi = fmask[bi];
  __syncthreads();
  bool mflag[2];
  unsigned long long ball[2];
#pragma unroll
  for (int u = 0; u < 2; ++u) {
    int j = u * 256 + tid;
    float fmj = fmask[b * L + j];
    bool aj = (1.0f - fmj) > 0.0f;
    bool ai = (1.0f - fmi) > 0.0f;
    int di = i - j;
    bool local_np = (di >= 9) || (di <= -8);
    int ad = di < 0 ? -di : di;
    bool dil_np = (ad & 15) != 0;
    bool m = (dil_np || aj || ai) && (local_np || aj);
    mflag[u] = m;
    ball[u] = __ballot(!m);
    if (lane == 0) wcnt[u * 4 + wv] = __popcll(ball[u]);
  }
  __syncthreads();
  if (tid == 0) {
    int s = 0;
    for (int w = 0; w < 8; ++w) { woff[w] = s; s += wcnt[w]; }
    njs = s;
  }
  __syncthreads();
#pragma unroll
  for (int u = 0; u < 2; ++u) {
    if (!mflag[u]) {
      int j = u * 256 + tid;
      int slot = woff[u * 4 + wv] + __popcll(ball[u] & ((1ull << lane) - 1ull));
      jlist[slot] = j;
      size_t pidx = ((size_t)bi * L + j) * 2;
      int p0 = (int)floorf(pos_ind[pidx]);
      int p1 = (int)floorf(pos_ind[pidx + 1]);
      p0s[slot] = min(max(p0, -64), 63) + 64;
      p1s[slot] = min(max(p1, -64), 63) + 192;
    }
  }
  __syncthreads();
  int nj = njs;
  const float scale = 0.17677669529663687f;
#pragma unroll
  for (int hu = 0; hu < 2; ++hu) {
    int h = wv + hu * 4;
    float sc = -1e30f;
    if (lane < nj) {
      int j = jlist[lane];
      const float4* kr4 = (const float4*)&kk[(size_t)(b * L + j) * D + h * DKK];
      const float4* qh4 = (const float4*)&qrow[h * DKK];
      float dot = 0.f;
#pragma unroll
      for (int dq = 0; dq < 8; ++dq) {
        float4 av = qh4[dq], bv = kr4[dq];
        dot += av.x * bv.x + av.y * bv.y + av.z * bv.z + av.w * bv.w;
      }
      sc = dot * scale + sT[p0s[lane] * 8 + h] + sT[p1s[lane] * 8 + h] + pbm[h];
    }
    float mx = sc;
#pragma unroll
    for (int m2 = 32; m2; m2 >>= 1) mx = fmaxf(mx, __shfl_xor(mx, m2));
    float e = (lane < nj) ? expf(sc - mx) : 0.0f;
    float ssum = e;
#pragma unroll
    for (int m2 = 32; m2; m2 >>= 1) ssum += __shfl_xor(ssum, m2);
    psh[h][lane] = e / ssum;
  }
  __syncthreads();
  int h2 = tid >> 5, d = tid & 31;
  float pv0 = 0.f, pv1 = 0.f;
  if (nj > 0) {
    int s2 = 0;
    for (; s2 + 1 < nj; s2 += 2) {
      pv0 += psh[h2][s2] * vv[(size_t)(b * L + jlist[s2]) * D + h2 * DKK + d];
      pv1 += psh[h2][s2 + 1] *
             vv[(size_t)(b * L + jlist[s2 + 1]) * D + h2 * DKK + d];
    }
    if (s2 < nj)
      pv0 += psh[h2][s2] * vv[(size_t)(b * L + jlist[s2]) * D + h2 * DKK + d];
  } else {
    for (int j = 0; j < L; ++j) pv0 += vv[(size_t)(b * L + j) * D + tid];
    pv0 *= (1.0f / L);
  }
  orow[tid] = pv0 + pv1;
  __syncthreads();
  float a0 = 0.f, a1 = 0.f, a2 = 0.f, a3 = 0.f;
  const float* wc = wo_l + tid;
  for (int kx = 0; kx < D; kx += 4) {
    a0 += orow[kx + 0] * wc[(size_t)(kx + 0) * D];
    a1 += orow[kx + 1] * wc[(size_t)(kx + 1) * D];
    a2 += orow[kx + 2] * wc[(size_t)(kx + 2) * D];
    a3 += orow[kx + 3] * wc[(size_t)(kx + 3) * D];
  }
  float o2 = (a0 + a1) + (a2 + a3);
  float val = xio[(size_t)bi * D + tid] + o2;
  float sum = val;
#pragma unroll
  for (int m2 = 32; m2; m2 >>= 1) sum += __shfl_xor(sum, m2);
  if (lane == 0) red[wv] = sum;
  __syncthreads();
  float mean = (red[0] + red[1] + red[2] + red[3]) * (1.0f / D);
  float dd = val - mean;
  float sq = dd * dd;
#pragma unroll
  for (int m2 = 32; m2; m2 >>= 1) sq += __shfl_xor(sq, m2);
  if (lane == 0) red[4 + wv] = sq;
  __syncthreads();
  float var = (red[4] + red[5] + red[6] + red[7]) * (1.0f / D);
  float rs = rsqrtf(var + 1e-5f);
  xio[(size_t)bi * D + tid] = dd * rs * g1[tid] + b1v[tid];
}

// ---------------------------------------------------------------------------
// x = LayerNorm(resid + sum(y[0..NY-1])) * g + b — one wave per row
// ---------------------------------------------------------------------------
template <int NY>
__global__ __launch_bounds__(256) void ln_kernel(
    const float* __restrict__ resid, const float* __restrict__ y0,
    const float* __restrict__ y1, const float* __restrict__ y2,
    const float* __restrict__ y3, const float* __restrict__ g,
    const float* __restrict__ bta, float* __restrict__ outx) {
  const float* ys[4] = {y0, y1, y2, y3};
  int t = threadIdx.x;
  int lane = t & 63;
  int row = blockIdx.x * 4 + (t >> 6);
  int base = row * D + lane * 4;
  float4 r = *(const float4*)&resid[base];
  float val[4] = {r.x, r.y, r.z, r.w};
#pragma unroll
  for (int n = 0; n < NY; ++n) {
    float4 yv = *(const float4*)&ys[n][base];
    val[0] += yv.x; val[1] += yv.y; val[2] += yv.z; val[3] += yv.w;
  }
  float s = val[0] + val[1] + val[2] + val[3];
#pragma unroll
  for (int m = 32; m; m >>= 1) s += __shfl_xor(s, m);
  float mean = s * (1.0f / D);
  float vv = 0.f;
#pragma unroll
  for (int e = 0; e < 4; ++e) {
    float dd = val[e] - mean;
    vv += dd * dd;
  }
#pragma unroll
  for (int m = 32; m; m >>= 1) vv += __shfl_xor(vv, m);
  float rs = rsqrtf(vv * (1.0f / D) + 1e-5f);
  float4 gv = *(const float4*)&g[lane * 4];
  float4 bv = *(const float4*)&bta[lane * 4];
  float4 ov;
  ov.x = (val[0] - mean) * rs * gv.x + bv.x;
  ov.y = (val[1] - mean) * rs * gv.y + bv.y;
  ov.z = (val[2] - mean) * rs * gv.z + bv.z;
  ov.w = (val[3] - mean) * rs * gv.w + bv.w;
  *(float4*)&outx[base] = ov;
}

// ---------------------------------------------------------------------------
// final: LN2(resid + sum y[0..3]) + classifier + 2-way softmax — wave per row
// ---------------------------------------------------------------------------
__global__ __launch_bounds__(256) void ln_cls_kernel(
    const float* __restrict__ resid, const float* __restrict__ y0,
    const float* __restrict__ y1, const float* __restrict__ y2,
    const float* __restrict__ y3, const float* __restrict__ g,
    const float* __restrict__ bta, const float* __restrict__ cw,
    const float* __restrict__ cb, float* __restrict__ out) {
  int t = threadIdx.x;
  int lane = t & 63;
  int row = blockIdx.x * 4 + (t >> 6);
  int base = row * D + lane * 4;
  float4 r = *(const float4*)&resid[base];
  float4 a = *(const float4*)&y0[base];
  float4 c = *(const float4*)&y1[base];
  float4 d2 = *(const float4*)&y2[base];
  float4 e2 = *(const float4*)&y3[base];
  float val[4] = {r.x + a.x + c.x + d2.x + e2.x,
                  r.y + a.y + c.y + d2.y + e2.y,
                  r.z + a.z + c.z + d2.z + e2.z,
                  r.w + a.w + c.w + d2.w + e2.w};
  float s = val[0] + val[1] + val[2] + val[3];
#pragma unroll
  for (int m = 32; m; m >>= 1) s += __shfl_xor(s, m);
  float mean = s * (1.0f / D);
  float vv = 0.f;
#pragma unroll
  for (int e = 0; e < 4; ++e) {
    float dd = val[e] - mean;
    vv += dd * dd;
  }
#pragma unroll
  for (int m = 32; m; m >>= 1) vv += __shfl_xor(vv, m);
  float rs = rsqrtf(vv * (1.0f / D) + 1e-5f);
  float4 gv = *(const float4*)&g[lane * 4];
  float4 bv = *(const float4*)&bta[lane * 4];
  float xv[4];
  xv[0] = (val[0] - mean) * rs * gv.x + bv.x;
  xv[1] = (val[1] - mean) * rs * gv.y + bv.y;
  xv[2] = (val[2] - mean) * rs * gv.z + bv.z;
  xv[3] = (val[3] - mean) * rs * gv.w + bv.w;
  float l0 = 0.f, l1 = 0.f;
#pragma unroll
  for (int e = 0; e < 4; ++e) {
    int col = lane * 4 + e;
    l0 += xv[e] * cw[col * NCLS + 0];
    l1 += xv[e] * cw[col * NCLS + 1];
  }
#pragma unroll
  for (int m = 32; m; m >>= 1) {
    l0 += __shfl_xor(l0, m);
    l1 += __shfl_xor(l1, m);
  }
  if (lane == 0) {
    l0 += cb[0];
    l1 += cb[1];
    float mx = fmaxf(l0, l1);
    float e0 = expf(l0 - mx), e1 = expf(l1 - mx);
    float inv = 1.0f / (e0 + e1);
    out[row * 2 + 0] = e0 * inv;
    out[row * 2 + 1] = e1 * inv;
  }
}

extern "C" void kernel_launch(void* const* d_in, const int* in_sizes, int n_in,
                              void* d_out, int out_size, void* d_ws,
                              size_t ws_size, hipStream_t stream) {
  const float* feature  = (const float*)d_in[0];
  const float* pos_ind  = (const float*)d_in[1];
  const float* fmaskp   = (const float*)d_in[2];
  const float* w_reduce = (const float*)d_in[3];
  const float* b_reduce = (const float*)d_in[4];
  const float* pos_w    = (const float*)d_in[5];
  const float* pos_b    = (const float*)d_in[6];
  const float* wq       = (const float*)d_in[7];
  const float* wk       = (const float*)d_in[8];
  const float* wv       = (const float*)d_in[9];
  const float* wo       = (const float*)d_in[10];
  const float* ln1_g    = (const float*)d_in[11];
  const float* ln1_b    = (const float*)d_in[12];
  const float* w1       = (const float*)d_in[13];
  const float* b1       = (const float*)d_in[14];
  const float* w2       = (const float*)d_in[15];
  const float* b2       = (const float*)d_in[16];
  const float* ln2_g    = (const float*)d_in[17];
  const float* ln2_b    = (const float*)d_in[18];
  const float* cls_w    = (const float*)d_in[19];
  const float* cls_b    = (const float*)d_in[20];
  float* out = (float*)d_out;

  float* ws = (float*)d_ws;
  float* x     = ws;  ws += B * L * D;
  float* q     = ws;  ws += B * L * D;
  float* kbuf  = ws;  ws += B * L * D;
  float* vbuf  = ws;  ws += B * L * D;
  float* tmp   = ws;  ws += B * L * D;
  float* tmp2  = ws;  ws += B * L * D;
  float* tmp3  = ws;  ws += B * L * D;
  float* tmp4  = ws;  ws += B * L * D;
  float* ffn_h = ws;  ws += B * L * DFF;
  float* T     = ws;  ws += 2048;
  float* pbm   = ws;  ws += 8;

  const int M = B * L;  // 1024

  prep_kernel<<<256, 512, 0, stream>>>(pos_w, pos_b, T, pbm);

  // reduce layer: split-K 2 at 208, then x = selu(tmp + tmp2)
  gemm_kernel<0, 2><<<dim3(M / 32, D / 64, 2), 256, 0, stream>>>(
      feature, w_reduce, nullptr, nullptr, b_reduce, tmp, tmp2, nullptr,
      nullptr, M, D, DIN, 208);
  selu_add_kernel<<<M * D / 1024, 256, 0, stream>>>(tmp, tmp2, x);

  for (int l = 0; l < NL; ++l) {
    // fused QKV (z selects matrix)
    gemm_kernel<0, 1><<<dim3(M / 32, D / 64, 3), 256, 0, stream>>>(
        x, wq + l * D * D, wk + l * D * D, wv + l * D * D, nullptr,
        q, kbuf, vbuf, nullptr, M, D, D, 0);

    // fused attention + wo + ln1 (writes x in place, row-local)
    k_attn<<<M, 256, 0, stream>>>(q, kbuf, vbuf, pos_ind, fmaskp, T, pbm, x,
                                  wo + l * D * D, ln1_g + l * D,
                                  ln1_b + l * D);

    // FFN up (relu)
    gemm_kernel<1, 0><<<dim3(M / 32, DFF / 64), 256, 0, stream>>>(
        x, w1 + l * D * DFF, nullptr, nullptr, b1 + l * DFF, ffn_h, nullptr,
        nullptr, nullptr, M, DFF, D, 0);
    // FFN down, split-K 4
    gemm_kernel<0, 3><<<dim3(M / 32, D / 64, 4), 256, 0, stream>>>(
        ffn_h, w2 + l * DFF * D, nullptr, nullptr, b2 + l * D, tmp, tmp2,
        tmp3, tmp4, M, D, DFF, 0);

    if (l == NL - 1) {
      ln_cls_kernel<<<M / 4, 256, 0, stream>>>(x, tmp, tmp2, tmp3, tmp4,
                                               ln2_g + l * D, ln2_b + l * D,
                                               cls_w, cls_b, out);
    } else {
      ln_kernel<4><<<M / 4, 256, 0, stream>>>(x, tmp, tmp2, tmp3, tmp4,
                                              ln2_g + l * D, ln2_b + l * D, x);
    }
  }
}

// Round 9
// 143.736 us; speedup vs baseline: 5.0581x; 1.0182x over previous
//
#include <hip/hip_runtime.h>
#include <math.h>

#define B 2
#define L 512
#define DIN 400
#define D 256
#define H 8
#define DKK 32
#define DFF 1024
#define NL 2
#define NCLS 2

// ---------------------------------------------------------------------------
// K1: fused [reduce GEMM + SELU] (tasks 0..127) | prep (tasks 128..383)
// GEMM body is R5-verbatim (double-buffered, BM32/BN64/BK16/TM2/TN4).
// ---------------------------------------------------------------------------
__global__ __launch_bounds__(256) void k_init(
    const float* __restrict__ feature, const float* __restrict__ w_reduce,
    const float* __restrict__ b_reduce, float* __restrict__ x,
    const float* __restrict__ pos_w, const float* __restrict__ pos_b,
    float* __restrict__ T, float* __restrict__ pbm) {
  __shared__ float As[2][32][20];
  __shared__ float Bs[2][16][68];
  int tid = threadIdx.x;
  int task = blockIdx.x;
  if (task >= 128) {
    // ---- prep task (R6-proven, 256 threads) ----
    int t = task - 128;
    int c = t >> 7;
    float p = (float)((t & 127) - 64);
    int h = tid >> 5;
    int r2 = tid & 31;
    float val = 0.f;
#pragma unroll
    for (int rr = 0; rr < 2; ++rr) {
      int r = r2 + rr * 32;
      float inv = powf(10000.0f, -(float)r * (1.0f / 64.0f));
      float a = p * inv;
      const float* ps = pos_w + (size_t)(c * 128 + r) * D + h * DKK;
      const float* pc = pos_w + (size_t)(c * 128 + 64 + r) * D + h * DKK;
      float ss = 0.f, cs = 0.f;
#pragma unroll
      for (int d = 0; d < DKK; d += 4) {
        float4 v1 = *(const float4*)&ps[d];
        float4 v2 = *(const float4*)&pc[d];
        ss += v1.x + v1.y + v1.z + v1.w;
        cs += v2.x + v2.y + v2.z + v2.w;
      }
      val += sinf(a) * ss + cosf(a) * cs;
    }
    val *= (1.0f / DKK);
#pragma unroll
    for (int m2 = 16; m2; m2 >>= 1) val += __shfl_xor(val, m2);
    if (r2 == 0) T[t * 8 + h] = val;
    if (t == 0) {
      float pv = pos_b[h * DKK + r2];
#pragma unroll
      for (int m2 = 16; m2; m2 >>= 1) pv += __shfl_xor(pv, m2);
      if (r2 == 0) pbm[h] = pv * (1.0f / DKK);
    }
    return;
  }
  // ---- reduce GEMM: x = selu(feature @ w_reduce + b_reduce) ----
  const int K = DIN, N = D;
  int m0 = (task >> 2) * 32;
  int n0 = (task & 3) * 64;
  int a_m = tid >> 3;
  int a_k = (tid & 7) * 2;
  int b_k = tid >> 4;
  int b_n = (tid & 15) * 4;
  const float* Aptr = feature + (size_t)(m0 + a_m) * K + a_k;
  const float* Wptr = w_reduce + (size_t)b_k * N + n0 + b_n;
  const int nT = K / 16;  // 25
  int tc = tid & 15;
  int tr = tid >> 4;
  float acc[2][4];
#pragma unroll
  for (int i = 0; i < 2; ++i)
#pragma unroll
    for (int j = 0; j < 4; ++j) acc[i][j] = 0.0f;

  float2 areg = *(const float2*)Aptr;
  float4 breg = *(const float4*)Wptr;
  int buf = 0;
  *(float2*)&As[0][a_m][a_k] = areg;
  *(float4*)&Bs[0][b_k][b_n] = breg;

  for (int t = 0; t < nT; ++t) {
    __syncthreads();
    if (t + 1 < nT) {
      areg = *(const float2*)(Aptr + (t + 1) * 16);
      breg = *(const float4*)(Wptr + (size_t)(t + 1) * 16 * N);
    }
#pragma unroll
    for (int k = 0; k < 16; ++k) {
      float a0 = As[buf][tr * 2 + 0][k];
      float a1 = As[buf][tr * 2 + 1][k];
      float4 b = *(const float4*)&Bs[buf][k][tc * 4];
      acc[0][0] += a0 * b.x; acc[0][1] += a0 * b.y;
      acc[0][2] += a0 * b.z; acc[0][3] += a0 * b.w;
      acc[1][0] += a1 * b.x; acc[1][1] += a1 * b.y;
      acc[1][2] += a1 * b.z; acc[1][3] += a1 * b.w;
    }
    __syncthreads();
    if (t + 1 < nT) {
      *(float2*)&As[buf ^ 1][a_m][a_k] = areg;
      *(float4*)&Bs[buf ^ 1][b_k][b_n] = breg;
    }
    buf ^= 1;
  }
  const float s_alpha = 1.6732632423543772f, s_scale = 1.0507009873554805f;
#pragma unroll
  for (int i = 0; i < 2; ++i) {
    int row = m0 + tr * 2 + i;
    float4 outv;
    float v;
    v = acc[i][0] + b_reduce[n0 + tc * 4 + 0];
    outv.x = s_scale * (v > 0.f ? v : s_alpha * expm1f(v));
    v = acc[i][1] + b_reduce[n0 + tc * 4 + 1];
    outv.y = s_scale * (v > 0.f ? v : s_alpha * expm1f(v));
    v = acc[i][2] + b_reduce[n0 + tc * 4 + 2];
    outv.z = s_scale * (v > 0.f ? v : s_alpha * expm1f(v));
    v = acc[i][3] + b_reduce[n0 + tc * 4 + 3];
    outv.w = s_scale * (v > 0.f ? v : s_alpha * expm1f(v));
    *(float4*)&x[(size_t)row * N + n0 + tc * 4] = outv;
  }
}

// ---------------------------------------------------------------------------
// double-buffered register-tiled GEMM (R5-verbatim): C = act(A @ W + bias)
// MODE 1: z selects (Wa->Ca)/(Wb->Cb)/(Wc->Cc). MODE 3: split-K 4.
// ACT: 0 none, 1 relu (MODE==0 only)
// ---------------------------------------------------------------------------
template <int ACT, int MODE>
__global__ __launch_bounds__(256) void gemm_kernel(
    const float* __restrict__ A, const float* __restrict__ Wa,
    const float* __restrict__ Wb, const float* __restrict__ Wc,
    const float* __restrict__ bias, float* __restrict__ Ca,
    float* __restrict__ Cb, float* __restrict__ Cc, float* __restrict__ Cd,
    int M, int N, int K, int kMid) {
  __shared__ float As[2][32][20];
  __shared__ float Bs[2][16][68];
  int tid = threadIdx.x;
  int m0 = blockIdx.x * 32;
  int n0 = blockIdx.y * 64;
  const float* W = Wa;
  float* C = Ca;
  int kBeg = 0, kEnd = K;
  bool useBias = (bias != nullptr);
  if (MODE == 1) {
    W = blockIdx.z == 0 ? Wa : (blockIdx.z == 1 ? Wb : Wc);
    C = blockIdx.z == 0 ? Ca : (blockIdx.z == 1 ? Cb : Cc);
  } else if (MODE == 2) {
    kBeg = blockIdx.z == 0 ? 0 : kMid;
    kEnd = blockIdx.z == 0 ? kMid : K;
    C = blockIdx.z == 0 ? Ca : Cb;
    if (blockIdx.z != 0) useBias = false;
  } else if (MODE == 3) {
    int q = K / 4;
    kBeg = blockIdx.z * q;
    kEnd = kBeg + q;
    C = blockIdx.z == 0 ? Ca
        : (blockIdx.z == 1 ? Cb : (blockIdx.z == 2 ? Cc : Cd));
    if (blockIdx.z != 0) useBias = false;
  }
  int a_m = tid >> 3;
  int a_k = (tid & 7) * 2;
  int b_k = tid >> 4;
  int b_n = (tid & 15) * 4;
  const float* Aptr = A + (size_t)(m0 + a_m) * K + kBeg + a_k;
  const float* Wptr = W + (size_t)(kBeg + b_k) * N + n0 + b_n;
  int nT = (kEnd - kBeg) / 16;
  int tc = tid & 15;
  int tr = tid >> 4;
  float acc[2][4];
#pragma unroll
  for (int i = 0; i < 2; ++i)
#pragma unroll
    for (int j = 0; j < 4; ++j) acc[i][j] = 0.0f;

  float2 areg = *(const float2*)Aptr;
  float4 breg = *(const float4*)Wptr;
  int buf = 0;
  *(float2*)&As[0][a_m][a_k] = areg;
  *(float4*)&Bs[0][b_k][b_n] = breg;

  for (int t = 0; t < nT; ++t) {
    __syncthreads();
    if (t + 1 < nT) {
      areg = *(const float2*)(Aptr + (t + 1) * 16);
      breg = *(const float4*)(Wptr + (size_t)(t + 1) * 16 * N);
    }
#pragma unroll
    for (int k = 0; k < 16; ++k) {
      float a0 = As[buf][tr * 2 + 0][k];
      float a1 = As[buf][tr * 2 + 1][k];
      float4 b = *(const float4*)&Bs[buf][k][tc * 4];
      acc[0][0] += a0 * b.x; acc[0][1] += a0 * b.y;
      acc[0][2] += a0 * b.z; acc[0][3] += a0 * b.w;
      acc[1][0] += a1 * b.x; acc[1][1] += a1 * b.y;
      acc[1][2] += a1 * b.z; acc[1][3] += a1 * b.w;
    }
    __syncthreads();
    if (t + 1 < nT) {
      *(float2*)&As[buf ^ 1][a_m][a_k] = areg;
      *(float4*)&Bs[buf ^ 1][b_k][b_n] = breg;
    }
    buf ^= 1;
  }
  float bb[4];
#pragma unroll
  for (int j = 0; j < 4; ++j) bb[j] = useBias ? bias[n0 + tc * 4 + j] : 0.0f;
#pragma unroll
  for (int i = 0; i < 2; ++i) {
    int row = m0 + tr * 2 + i;
    float4 outv;
    float v0 = acc[i][0] + bb[0], v1 = acc[i][1] + bb[1];
    float v2 = acc[i][2] + bb[2], v3 = acc[i][3] + bb[3];
    if (MODE == 0 && ACT == 1) {
      v0 = fmaxf(v0, 0.f); v1 = fmaxf(v1, 0.f);
      v2 = fmaxf(v2, 0.f); v3 = fmaxf(v3, 0.f);
    }
    outv.x = v0; outv.y = v1; outv.z = v2; outv.w = v3;
    *(float4*)&C[(size_t)row * N + n0 + tc * 4] = outv;
  }
}

// ---------------------------------------------------------------------------
// fused attn + wo + ln1, one row per block (256 threads) — R8-verbatim
// ---------------------------------------------------------------------------
__global__ __launch_bounds__(256) void k_attn(
    const float* __restrict__ q, const float* __restrict__ kk,
    const float* __restrict__ vv, const float* __restrict__ pos_ind,
    const float* __restrict__ fmask, const float* __restrict__ Tg,
    const float* __restrict__ pbm, float* __restrict__ xio,
    const float* __restrict__ wo_l, const float* __restrict__ g1,
    const float* __restrict__ b1v) {
  __shared__ float sT[2048];
  __shared__ float qrow[256];
  __shared__ float orow[256];
  __shared__ float psh[8][64];
  __shared__ float red[8];
  __shared__ int jlist[64], p0s[64], p1s[64], wcnt[8], woff[8], njs;
  int tid = threadIdx.x;
  int lane = tid & 63;
  int wv = tid >> 6;
  int bi = blockIdx.x;
  int b = bi >> 9, i = bi & 511;
  for (int e = tid; e < 2048; e += 256) sT[e] = Tg[e];
  qrow[tid] = q[(size_t)bi * D + tid];
  float fmi = fmask[bi];
  __syncthreads();
  bool mflag[2];
  unsigned long long ball[2];
#pragma unroll
  for (int u = 0; u < 2; ++u) {
    int j = u * 256 + tid;
    float fmj = fmask[b * L + j];
    bool aj = (1.0f - fmj) > 0.0f;
    bool ai = (1.0f - fmi) > 0.0f;
    int di = i - j;
    bool local_np = (di >= 9) || (di <= -8);
    int ad = di < 0 ? -di : di;
    bool dil_np = (ad & 15) != 0;
    bool m = (dil_np || aj || ai) && (local_np || aj);
    mflag[u] = m;
    ball[u] = __ballot(!m);
    if (lane == 0) wcnt[u * 4 + wv] = __popcll(ball[u]);
  }
  __syncthreads();
  if (tid == 0) {
    int s = 0;
    for (int w = 0; w < 8; ++w) { woff[w] = s; s += wcnt[w]; }
    njs = s;
  }
  __syncthreads();
#pragma unroll
  for (int u = 0; u < 2; ++u) {
    if (!mflag[u]) {
      int j = u * 256 + tid;
      int slot = woff[u * 4 + wv] + __popcll(ball[u] & ((1ull << lane) - 1ull));
      jlist[slot] = j;
      size_t pidx = ((size_t)bi * L + j) * 2;
      int p0 = (int)floorf(pos_ind[pidx]);
      int p1 = (int)floorf(pos_ind[pidx + 1]);
      p0s[slot] = min(max(p0, -64), 63) + 64;
      p1s[slot] = min(max(p1, -64), 63) + 192;
    }
  }
  __syncthreads();
  int nj = njs;
  const float scale = 0.17677669529663687f;
#pragma unroll
  for (int hu = 0; hu < 2; ++hu) {
    int h = wv + hu * 4;
    float sc = -1e30f;
    if (lane < nj) {
      int j = jlist[lane];
      const float4* kr4 = (const float4*)&kk[(size_t)(b * L + j) * D + h * DKK];
      const float4* qh4 = (const float4*)&qrow[h * DKK];
      float dot = 0.f;
#pragma unroll
      for (int dq = 0; dq < 8; ++dq) {
        float4 av = qh4[dq], bv = kr4[dq];
        dot += av.x * bv.x + av.y * bv.y + av.z * bv.z + av.w * bv.w;
      }
      sc = dot * scale + sT[p0s[lane] * 8 + h] + sT[p1s[lane] * 8 + h] + pbm[h];
    }
    float mx = sc;
#pragma unroll
    for (int m2 = 32; m2; m2 >>= 1) mx = fmaxf(mx, __shfl_xor(mx, m2));
    float e = (lane < nj) ? expf(sc - mx) : 0.0f;
    float ssum = e;
#pragma unroll
    for (int m2 = 32; m2; m2 >>= 1) ssum += __shfl_xor(ssum, m2);
    psh[h][lane] = e / ssum;
  }
  __syncthreads();
  int h2 = tid >> 5, d = tid & 31;
  float pv0 = 0.f, pv1 = 0.f;
  if (nj > 0) {
    int s2 = 0;
    for (; s2 + 1 < nj; s2 += 2) {
      pv0 += psh[h2][s2] * vv[(size_t)(b * L + jlist[s2]) * D + h2 * DKK + d];
      pv1 += psh[h2][s2 + 1] *
             vv[(size_t)(b * L + jlist[s2 + 1]) * D + h2 * DKK + d];
    }
    if (s2 < nj)
      pv0 += psh[h2][s2] * vv[(size_t)(b * L + jlist[s2]) * D + h2 * DKK + d];
  } else {
    for (int j = 0; j < L; ++j) pv0 += vv[(size_t)(b * L + j) * D + tid];
    pv0 *= (1.0f / L);
  }
  orow[tid] = pv0 + pv1;
  __syncthreads();
  float a0 = 0.f, a1 = 0.f, a2 = 0.f, a3 = 0.f;
  const float* wc = wo_l + tid;
  for (int kx = 0; kx < D; kx += 4) {
    a0 += orow[kx + 0] * wc[(size_t)(kx + 0) * D];
    a1 += orow[kx + 1] * wc[(size_t)(kx + 1) * D];
    a2 += orow[kx + 2] * wc[(size_t)(kx + 2) * D];
    a3 += orow[kx + 3] * wc[(size_t)(kx + 3) * D];
  }
  float o2 = (a0 + a1) + (a2 + a3);
  float val = xio[(size_t)bi * D + tid] + o2;
  float sum = val;
#pragma unroll
  for (int m2 = 32; m2; m2 >>= 1) sum += __shfl_xor(sum, m2);
  if (lane == 0) red[wv] = sum;
  __syncthreads();
  float mean = (red[0] + red[1] + red[2] + red[3]) * (1.0f / D);
  float dd = val - mean;
  float sq = dd * dd;
#pragma unroll
  for (int m2 = 32; m2; m2 >>= 1) sq += __shfl_xor(sq, m2);
  if (lane == 0) red[4 + wv] = sq;
  __syncthreads();
  float var = (red[4] + red[5] + red[6] + red[7]) * (1.0f / D);
  float rs = rsqrtf(var + 1e-5f);
  xio[(size_t)bi * D + tid] = dd * rs * g1[tid] + b1v[tid];
}

// ---------------------------------------------------------------------------
// ln2(l) fused with qkv(l+1) — R7-proven (hand-inlined). grid (32,4,3).
// ---------------------------------------------------------------------------
__global__ __launch_bounds__(256) void k_ln2qkv(
    const float* __restrict__ xold, const float* __restrict__ t1,
    const float* __restrict__ t2, const float* __restrict__ t3,
    const float* __restrict__ t4, const float* __restrict__ g,
    const float* __restrict__ bta, const float* __restrict__ wq_l,
    const float* __restrict__ wk_l, const float* __restrict__ wv_l,
    float* __restrict__ q, float* __restrict__ kbuf, float* __restrict__ vbuf,
    float* __restrict__ xnew) {
  __shared__ float xs[32][260];
  __shared__ float Bs[2][16][68];
  int tid = threadIdx.x;
  int lane = tid & 63, wv = tid >> 6;
  int m0 = blockIdx.x * 32;
  for (int r8 = 0; r8 < 8; ++r8) {
    int lr = wv * 8 + r8;
    int base = (m0 + lr) * D + lane * 4;
    float4 r = *(const float4*)&xold[base];
    float4 y0 = *(const float4*)&t1[base];
    float4 y1 = *(const float4*)&t2[base];
    float4 y2 = *(const float4*)&t3[base];
    float4 y3 = *(const float4*)&t4[base];
    float val[4] = {r.x + y0.x + y1.x + y2.x + y3.x,
                    r.y + y0.y + y1.y + y2.y + y3.y,
                    r.z + y0.z + y1.z + y2.z + y3.z,
                    r.w + y0.w + y1.w + y2.w + y3.w};
    float s = val[0] + val[1] + val[2] + val[3];
#pragma unroll
    for (int m = 32; m; m >>= 1) s += __shfl_xor(s, m);
    float mean = s * (1.0f / D);
    float vvv = 0.f;
#pragma unroll
    for (int e = 0; e < 4; ++e) {
      float dd = val[e] - mean;
      vvv += dd * dd;
    }
#pragma unroll
    for (int m = 32; m; m >>= 1) vvv += __shfl_xor(vvv, m);
    float rs = rsqrtf(vvv * (1.0f / D) + 1e-5f);
    float4 gv = *(const float4*)&g[lane * 4];
    float4 bv = *(const float4*)&bta[lane * 4];
    float4 ov;
    ov.x = (val[0] - mean) * rs * gv.x + bv.x;
    ov.y = (val[1] - mean) * rs * gv.y + bv.y;
    ov.z = (val[2] - mean) * rs * gv.z + bv.z;
    ov.w = (val[3] - mean) * rs * gv.w + bv.w;
    *(float4*)&xs[lr][lane * 4] = ov;
  }
  __syncthreads();
  int z = blockIdx.z;
  const float* W = z == 0 ? wq_l : (z == 1 ? wk_l : wv_l);
  float* C = z == 0 ? q : (z == 1 ? kbuf : vbuf);
  int n0 = blockIdx.y * 64;
  int b_k = tid >> 4, b_n = (tid & 15) * 4;
  const float* Wptr = W + (size_t)b_k * D + n0 + b_n;
  int tc = tid & 15, tr = tid >> 4;
  float acc[2][4] = {{0, 0, 0, 0}, {0, 0, 0, 0}};
  float4 breg = *(const float4*)Wptr;
  int buf = 0;
  *(float4*)&Bs[0][b_k][b_n] = breg;
  for (int t = 0; t < 16; ++t) {
    __syncthreads();
    if (t + 1 < 16) breg = *(const float4*)(Wptr + (size_t)(t + 1) * 16 * D);
#pragma unroll
    for (int k = 0; k < 16; ++k) {
      float a0 = xs[tr * 2 + 0][t * 16 + k];
      float a1 = xs[tr * 2 + 1][t * 16 + k];
      float4 bvv = *(const float4*)&Bs[buf][k][tc * 4];
      acc[0][0] += a0 * bvv.x; acc[0][1] += a0 * bvv.y;
      acc[0][2] += a0 * bvv.z; acc[0][3] += a0 * bvv.w;
      acc[1][0] += a1 * bvv.x; acc[1][1] += a1 * bvv.y;
      acc[1][2] += a1 * bvv.z; acc[1][3] += a1 * bvv.w;
    }
    __syncthreads();
    if (t + 1 < 16) *(float4*)&Bs[buf ^ 1][b_k][b_n] = breg;
    buf ^= 1;
  }
#pragma unroll
  for (int i = 0; i < 2; ++i) {
    float4 o4 = {acc[i][0], acc[i][1], acc[i][2], acc[i][3]};
    *(float4*)&C[(size_t)(m0 + tr * 2 + i) * D + n0 + tc * 4] = o4;
  }
  if (blockIdx.y == 0 && z == 0) {
    for (int e = tid; e < 2048; e += 256) {
      int lr = e >> 6, c4 = e & 63;
      *(float4*)&xnew[(size_t)(m0 + lr) * D + c4 * 4] =
          *(const float4*)&xs[lr][c4 * 4];
    }
  }
}

// ---------------------------------------------------------------------------
// final: LN2(resid + sum y[0..3]) + classifier + 2-way softmax — wave per row
// ---------------------------------------------------------------------------
__global__ __launch_bounds__(256) void ln_cls_kernel(
    const float* __restrict__ resid, const float* __restrict__ y0,
    const float* __restrict__ y1, const float* __restrict__ y2,
    const float* __restrict__ y3, const float* __restrict__ g,
    const float* __restrict__ bta, const float* __restrict__ cw,
    const float* __restrict__ cb, float* __restrict__ out) {
  int t = threadIdx.x;
  int lane = t & 63;
  int row = blockIdx.x * 4 + (t >> 6);
  int base = row * D + lane * 4;
  float4 r = *(const float4*)&resid[base];
  float4 a = *(const float4*)&y0[base];
  float4 c = *(const float4*)&y1[base];
  float4 d2 = *(const float4*)&y2[base];
  float4 e2 = *(const float4*)&y3[base];
  float val[4] = {r.x + a.x + c.x + d2.x + e2.x,
                  r.y + a.y + c.y + d2.y + e2.y,
                  r.z + a.z + c.z + d2.z + e2.z,
                  r.w + a.w + c.w + d2.w + e2.w};
  float s = val[0] + val[1] + val[2] + val[3];
#pragma unroll
  for (int m = 32; m; m >>= 1) s += __shfl_xor(s, m);
  float mean = s * (1.0f / D);
  float vv = 0.f;
#pragma unroll
  for (int e = 0; e < 4; ++e) {
    float dd = val[e] - mean;
    vv += dd * dd;
  }
#pragma unroll
  for (int m = 32; m; m >>= 1) vv += __shfl_xor(vv, m);
  float rs = rsqrtf(vv * (1.0f / D) + 1e-5f);
  float4 gv = *(const float4*)&g[lane * 4];
  float4 bv = *(const float4*)&bta[lane * 4];
  float xv[4];
  xv[0] = (val[0] - mean) * rs * gv.x + bv.x;
  xv[1] = (val[1] - mean) * rs * gv.y + bv.y;
  xv[2] = (val[2] - mean) * rs * gv.z + bv.z;
  xv[3] = (val[3] - mean) * rs * gv.w + bv.w;
  float l0 = 0.f, l1 = 0.f;
#pragma unroll
  for (int e = 0; e < 4; ++e) {
    int col = lane * 4 + e;
    l0 += xv[e] * cw[col * NCLS + 0];
    l1 += xv[e] * cw[col * NCLS + 1];
  }
#pragma unroll
  for (int m = 32; m; m >>= 1) {
    l0 += __shfl_xor(l0, m);
    l1 += __shfl_xor(l1, m);
  }
  if (lane == 0) {
    l0 += cb[0];
    l1 += cb[1];
    float mx = fmaxf(l0, l1);
    float e0 = expf(l0 - mx), e1 = expf(l1 - mx);
    float inv = 1.0f / (e0 + e1);
    out[row * 2 + 0] = e0 * inv;
    out[row * 2 + 1] = e1 * inv;
  }
}

extern "C" void kernel_launch(void* const* d_in, const int* in_sizes, int n_in,
                              void* d_out, int out_size, void* d_ws,
                              size_t ws_size, hipStream_t stream) {
  const float* feature  = (const float*)d_in[0];
  const float* pos_ind  = (const float*)d_in[1];
  const float* fmaskp   = (const float*)d_in[2];
  const float* w_reduce = (const float*)d_in[3];
  const float* b_reduce = (const float*)d_in[4];
  const float* pos_w    = (const float*)d_in[5];
  const float* pos_b    = (const float*)d_in[6];
  const float* wq       = (const float*)d_in[7];
  const float* wk       = (const float*)d_in[8];
  const float* wv       = (const float*)d_in[9];
  const float* wo       = (const float*)d_in[10];
  const float* ln1_g    = (const float*)d_in[11];
  const float* ln1_b    = (const float*)d_in[12];
  const float* w1       = (const float*)d_in[13];
  const float* b1       = (const float*)d_in[14];
  const float* w2       = (const float*)d_in[15];
  const float* b2       = (const float*)d_in[16];
  const float* ln2_g    = (const float*)d_in[17];
  const float* ln2_b    = (const float*)d_in[18];
  const float* cls_w    = (const float*)d_in[19];
  const float* cls_b    = (const float*)d_in[20];
  float* out = (float*)d_out;

  float* ws = (float*)d_ws;
  float* x0    = ws;  ws += B * L * D;
  float* x1    = ws;  ws += B * L * D;
  float* q     = ws;  ws += B * L * D;
  float* kbuf  = ws;  ws += B * L * D;
  float* vbuf  = ws;  ws += B * L * D;
  float* tmp1  = ws;  ws += B * L * D;
  float* tmp2  = ws;  ws += B * L * D;
  float* tmp3  = ws;  ws += B * L * D;
  float* tmp4  = ws;  ws += B * L * D;
  float* ffn_h = ws;  ws += B * L * DFF;
  float* T     = ws;  ws += 2048;
  float* pbm   = ws;  ws += 8;

  const int M = B * L;  // 1024

  // K1: reduce GEMM + selu + prep, one dispatch
  k_init<<<384, 256, 0, stream>>>(feature, w_reduce, b_reduce, x0, pos_w,
                                  pos_b, T, pbm);
  // layer 0
  gemm_kernel<0, 1><<<dim3(32, 4, 3), 256, 0, stream>>>(
      x0, wq, wk, wv, nullptr, q, kbuf, vbuf, nullptr, M, D, D, 0);
  k_attn<<<M, 256, 0, stream>>>(q, kbuf, vbuf, pos_ind, fmaskp, T, pbm, x0,
                                wo, ln1_g, ln1_b);
  gemm_kernel<1, 0><<<dim3(32, 16), 256, 0, stream>>>(
      x0, w1, nullptr, nullptr, b1, ffn_h, nullptr, nullptr, nullptr, M, DFF,
      D, 0);
  gemm_kernel<0, 3><<<dim3(32, 4, 4), 256, 0, stream>>>(
      ffn_h, w2, nullptr, nullptr, b2, tmp1, tmp2, tmp3, tmp4, M, D, DFF, 0);
  // ln2(l0) + qkv(l1), writes x1
  k_ln2qkv<<<dim3(32, 4, 3), 256, 0, stream>>>(
      x0, tmp1, tmp2, tmp3, tmp4, ln2_g, ln2_b, wq + D * D, wk + D * D,
      wv + D * D, q, kbuf, vbuf, x1);
  // layer 1
  k_attn<<<M, 256, 0, stream>>>(q, kbuf, vbuf, pos_ind, fmaskp, T, pbm, x1,
                                wo + D * D, ln1_g + D, ln1_b + D);
  gemm_kernel<1, 0><<<dim3(32, 16), 256, 0, stream>>>(
      x1, w1 + D * DFF, nullptr, nullptr, b1 + DFF, ffn_h, nullptr, nullptr,
      nullptr, M, DFF, D, 0);
  gemm_kernel<0, 3><<<dim3(32, 4, 4), 256, 0, stream>>>(
      ffn_h, w2 + DFF * D, nullptr, nullptr, b2 + D, tmp1, tmp2, tmp3, tmp4,
      M, D, DFF, 0);
  ln_cls_kernel<<<M / 4, 256, 0, stream>>>(x1, tmp1, tmp2, tmp3, tmp4,
                                           ln2_g + D, ln2_b + D, cls_w, cls_b,
                                           out);
}